// Round 4
// baseline (590.985 us; speedup 1.0000x reference)
//
#include <hip/hip_runtime.h>

typedef unsigned short u16;
typedef unsigned short u16x4 __attribute__((ext_vector_type(4)));
typedef unsigned short u16x8 __attribute__((ext_vector_type(8)));
typedef short bf16x8 __attribute__((ext_vector_type(8)));
typedef float f32x4 __attribute__((ext_vector_type(4)));

#define EPSF 1e-5f

// Geometry
#define C1   512
#define C2   128
#define C3   32
#define HH   28
#define WW   28
#define HW   784            // 28*28
#define NHW  50176          // 64*784
#define XELEMS 25690112     // 64*512*784
#define NGROUPS 6422528     // XELEMS/4

#define GRID 512            // 2 blocks/CU, resident by construction
#define XBLOCKS 510
#define W1_BLOCK 510
#define W2_BLOCK 511
#define CONV1_BLOCKS 392    // NHW/128
#define CONV2_JOBS 784      // NHW/64

// ws layout (bytes)
#define WS_WQ1    5376      // 128*512 bf16   -> ends 136448
#define WS_WQ2    136448    // 9*32*128 bf16  -> ends 210176
#define WS_P1     210176    // 510 float2 partials (x scan)
#define WS_P2     226560    // 392 float2 partials (conv1) -> ends 229696
#define WS_BAR    229696    // grid-barrier counter (zeroed by init kernel)
#define WS_H2     233472    // 50176*128 bf16 (NHWC)

__device__ __forceinline__ float bf2f(u16 u) { return __uint_as_float(((unsigned)u) << 16); }
__device__ __forceinline__ u16 f2bf(float f) {
  unsigned x = __float_as_uint(f);
  return (u16)((x + 0x7fffu + ((x >> 16) & 1u)) >> 16);
}
__device__ __forceinline__ float finz(float f) {
  unsigned u = __float_as_uint(f);
  return ((u & 0x7f800000u) == 0x7f800000u) ? 0.0f : f;
}

// block-level min/max reduce; result valid on threadIdx.x==0
__device__ __forceinline__ void block_minmax(float& mn, float& mx) {
  for (int m = 32; m; m >>= 1) {
    mn = fminf(mn, __shfl_xor(mn, m));
    mx = fmaxf(mx, __shfl_xor(mx, m));
  }
  __shared__ float wmn[4], wmx[4];
  const int wv = threadIdx.x >> 6;
  if ((threadIdx.x & 63) == 0) { wmn[wv] = mn; wmx[wv] = mx; }
  __syncthreads();
  if (threadIdx.x == 0) {
    mn = fminf(fminf(wmn[0], wmn[1]), fminf(wmn[2], wmn[3]));
    mx = fmaxf(fmaxf(wmx[0], wmx[1]), fmaxf(wmx[2], wmx[3]));
  }
}

// Software grid barrier. Safe because all GRID blocks are co-resident
// (2 blocks/CU guaranteed by __launch_bounds__(256,2) + 46.1KB LDS).
// Release: syncthreads drains stores -> threadfence -> acq_rel atomic at
// the coherence point. Acquire: agent-scope acquire spin-load ->
// syncthreads -> threadfence by all threads so later plain loads can't
// hit stale per-XCD L2/L1 lines.
__device__ __forceinline__ void grid_barrier(unsigned* bar, unsigned target) {
  __syncthreads();
  if (threadIdx.x == 0) {
    __threadfence();
    __hip_atomic_fetch_add(bar, 1u, __ATOMIC_ACQ_REL, __HIP_MEMORY_SCOPE_AGENT);
    while (__hip_atomic_load(bar, __ATOMIC_ACQUIRE, __HIP_MEMORY_SCOPE_AGENT) < target) {
      __builtin_amdgcn_s_sleep(2);
    }
  }
  __syncthreads();
  __threadfence();
}

__global__ void bar_init_kernel(unsigned char* ws) {
  if (threadIdx.x == 0) {
    __hip_atomic_store((unsigned*)(ws + WS_BAR), 0u, __ATOMIC_RELEASE,
                       __HIP_MEMORY_SCOPE_AGENT);
  }
}

// ---------------------------------------------------------------------------
// One fused kernel (plain launch + software grid barrier):
//  phase 0: blocks 0..509  -> min/max of relu(bn1(x))   (BN tables in LDS)
//           block 510      -> w1 minmax + quantize (single block, hidden)
//           block 511      -> w2 minmax + quantize+pack (single block, hidden)
//  barrier (512)
//  phase 1: blocks 0..391  -> conv1 128x128 MFMA tile (double-buffered LDS)
//  barrier (1024)
//  phase 2: all blocks     -> conv2 jobs (784 over 512, XCD-swizzled)
// ---------------------------------------------------------------------------
__global__ __launch_bounds__(256, 2) void fused_kernel(
    const float* __restrict__ x, const float* g1, const float* be1,
    const float* m1, const float* v1, const float* w1,
    const float* g2, const float* be2, const float* m2, const float* v2,
    const float* w2, unsigned char* ws, float* __restrict__ out) {
  __shared__ __align__(16) u16 Alds[2][128 * 40];
  __shared__ __align__(16) u16 Blds[2][128 * 40];
  __shared__ float bn1iL[C1], bn1bL[C1];
  __shared__ float bn2iL[C2], bn2bL[C2];
  __shared__ float bc[2];
  __shared__ float wred[8];

  const int t = threadIdx.x;
  const int bid = blockIdx.x;

  float2* p1 = (float2*)(ws + WS_P1);
  float2* p2 = (float2*)(ws + WS_P2);
  u16* wq1 = (u16*)(ws + WS_WQ1);
  u16* wq2 = (u16*)(ws + WS_WQ2);
  u16* h2 = (u16*)(ws + WS_H2);
  unsigned* bar = (unsigned*)(ws + WS_BAR);

  // per-block BN tables in LDS
  for (int c = t; c < C1; c += 256) {
    float inv = g1[c] / sqrtf(v1[c] + EPSF);
    bn1iL[c] = inv;
    bn1bL[c] = be1[c] - m1[c] * inv;
  }
  if (t < C2) {
    float inv = g2[t] / sqrtf(v2[t] + EPSF);
    bn2iL[t] = inv;
    bn2bL[t] = be2[t] - m2[t] * inv;
  }
  __syncthreads();

  // ------------------------------ phase 0 ---------------------------------
  if (bid < XBLOCKS) {
    const f32x4* x4 = (const f32x4*)x;
    float mn = 3.4e38f, mx = 0.0f;
    auto proc = [&](f32x4 u, int c) {
      float inv = bn1iL[c], bb = bn1bL[c];
#pragma unroll
      for (int j = 0; j < 4; j++) {
        float f = fmaxf(fmaf(u[j], inv, bb), 0.0f);
        mn = fminf(mn, f); mx = fmaxf(mx, f);
      }
    };
    const int S = XBLOCKS * 256;
    int i = bid * 256 + t;
    for (; i + 3 * S < NGROUPS; i += 4 * S) {
      f32x4 u0 = x4[i];
      f32x4 u1 = x4[i + S];
      f32x4 u2 = x4[i + 2 * S];
      f32x4 u3 = x4[i + 3 * S];
      int c0 = (i / 196) & (C1 - 1);
      int c1 = ((i + S) / 196) & (C1 - 1);
      int c2 = ((i + 2 * S) / 196) & (C1 - 1);
      int c3 = ((i + 3 * S) / 196) & (C1 - 1);
      proc(u0, c0); proc(u1, c1); proc(u2, c2); proc(u3, c3);
    }
    for (; i < NGROUPS; i += S) {
      f32x4 u = x4[i];
      proc(u, (i / 196) & (C1 - 1));
    }
    block_minmax(mn, mx);
    if (t == 0) p1[bid] = make_float2(mn, mx);
  } else if (bid == W1_BLOCK) {
    // whole w1 (128x512 f32) in one block: minmax, then quantize
    const f32x4* w4 = (const f32x4*)w1;
    float mn = 3.4e38f, mx = -3.4e38f;
#pragma unroll 8
    for (int k = t; k < 16384; k += 256) {
      f32x4 v = w4[k];
#pragma unroll
      for (int j = 0; j < 4; j++) {
        float f = finz(v[j]); mn = fminf(mn, f); mx = fmaxf(mx, f);
      }
    }
    block_minmax(mn, mx);
    if (t == 0) { bc[0] = mn; bc[1] = mx; }
    __syncthreads();
    const float mnv = bc[0];
    const float s = fmaxf((bc[1] - mnv) / 255.0f, 1e-8f);
    const float rs = 1.0f / s;
#pragma unroll 4
    for (int k = t; k < 16384; k += 256) {
      f32x4 v = w4[k];
      u16x4 o;
#pragma unroll
      for (int j = 0; j < 4; j++)
        o[j] = f2bf(fmaf(rintf((finz(v[j]) - mnv) * rs), s, mnv));
      *(u16x4*)(wq1 + k * 4) = o;
    }
  } else {
    // whole w2 (32x128x3x3 f32) in one block: minmax, quant+pack
    const f32x4* w4 = (const f32x4*)w2;
    float mn = 3.4e38f, mx = -3.4e38f;
#pragma unroll 4
    for (int k = t; k < 9216; k += 256) {
      f32x4 v = w4[k];
#pragma unroll
      for (int j = 0; j < 4; j++) {
        float f = finz(v[j]); mn = fminf(mn, f); mx = fmaxf(mx, f);
      }
    }
    block_minmax(mn, mx);
    if (t == 0) { bc[0] = mn; bc[1] = mx; }
    __syncthreads();
    const float mnv = bc[0];
    const float s = fmaxf((bc[1] - mnv) / 255.0f, 1e-8f);
    const float rs = 1.0f / s;
    // wq2 layout: tap*4096 + co*128 + ci  <- w2[(co*128+ci)*9 + tap]
    for (int jj = t; jj < 36864; jj += 256) {
      int tap = jj >> 12;
      int rem = jj & 4095;
      float f = finz(w2[rem * 9 + tap]);
      wq2[jj] = f2bf(fmaf(rintf((f - mnv) * rs), s, mnv));
    }
  }

  grid_barrier(bar, GRID);

  // ------------------------------ phase 1: conv1 --------------------------
  if (bid < CONV1_BLOCKS) {
    const int sp0 = bid * 128;

    // preamble: reduce 510 x-minmax partials
    {
      float mn = 3.4e38f, mx = 0.0f;
      for (int i = t; i < XBLOCKS; i += 256) {
        float2 p = p1[i];
        mn = fminf(mn, p.x); mx = fmaxf(mx, p.y);
      }
      block_minmax(mn, mx);
      if (t == 0) { bc[0] = mn; bc[1] = mx; }
      __syncthreads();
    }
    const float mn1 = bc[0];
    const float s1 = fmaxf((bc[1] - mn1) / 255.0f, 1e-8f);
    const float r1 = 1.0f / s1;

    // x staging: thread -> k-row kk (0..31), sp groups of 8 in both halves
    const int kk = t >> 3;
    const int spA = (t & 7) * 8;
    const int spB = 64 + spA;
    const int ga = sp0 + spA, gb = sp0 + spB;
    const int na = ga / HW, hwa = ga % HW;
    const int nb = gb / HW, hwb = gb % HW;
    const float* xA = x + na * (C1 * HW) + hwa;
    const float* xB = x + nb * (C1 * HW) + hwb;
    const int colg = (kk & 7) + 8 * ((((kk >> 3) + (spA >> 3))) & 3);

    // wq1 staging: thread -> co = t>>1, k offset (t&1)*16
    const int wco = t >> 1;
    const int wko = (t & 1) * 16;
    const int ab0 = wko >> 3;
    const int aswz = (wco >> 3) & 3;

    const int lane = t & 63;
    const int l15 = lane & 15;
    const int q = lane >> 4;
    const int wv = t >> 6;
    const int wy = wv >> 1;
    const int wx = wv & 1;

    f32x4 acc[4][4] = {};

    // prologue: load k=0 slice into registers
    u16x8 a0 = *(const u16x8*)(wq1 + wco * C1 + wko);
    u16x8 a1 = *(const u16x8*)(wq1 + wco * C1 + wko + 8);
    f32x4 va0 = *(const f32x4*)(xA + kk * HW);
    f32x4 va1 = *(const f32x4*)(xA + kk * HW + 4);
    f32x4 vb0 = *(const f32x4*)(xB + kk * HW);
    f32x4 vb1 = *(const f32x4*)(xB + kk * HW + 4);
    float inv = bn1iL[kk], bb = bn1bL[kk];

#pragma unroll 1
    for (int i = 0; i < 16; i++) {
      const int cur = i & 1;
      *(u16x8*)&Alds[cur][wco * 40 + (((ab0 + 0 + aswz) & 3) << 3)] = a0;
      *(u16x8*)&Alds[cur][wco * 40 + (((ab0 + 1 + aswz) & 3) << 3)] = a1;
#pragma unroll
      for (int j = 0; j < 4; j++) {
        float f0 = fmaxf(fmaf(va0[j], inv, bb), 0.0f);
        Blds[cur][(spA + j) * 40 + colg] = f2bf(fmaf(rintf((f0 - mn1) * r1), s1, mn1));
        float f1 = fmaxf(fmaf(va1[j], inv, bb), 0.0f);
        Blds[cur][(spA + 4 + j) * 40 + colg] = f2bf(fmaf(rintf((f1 - mn1) * r1), s1, mn1));
        float g0 = fmaxf(fmaf(vb0[j], inv, bb), 0.0f);
        Blds[cur][(spB + j) * 40 + colg] = f2bf(fmaf(rintf((g0 - mn1) * r1), s1, mn1));
        float g1v = fmaxf(fmaf(vb1[j], inv, bb), 0.0f);
        Blds[cur][(spB + 4 + j) * 40 + colg] = f2bf(fmaf(rintf((g1v - mn1) * r1), s1, mn1));
      }
      if (i < 15) {
        const int kn = (i + 1) * 32;
        a0 = *(const u16x8*)(wq1 + wco * C1 + kn + wko);
        a1 = *(const u16x8*)(wq1 + wco * C1 + kn + wko + 8);
        const int c = kn + kk;
        va0 = *(const f32x4*)(xA + c * HW);
        va1 = *(const f32x4*)(xA + c * HW + 4);
        vb0 = *(const f32x4*)(xB + c * HW);
        vb1 = *(const f32x4*)(xB + c * HW + 4);
        inv = bn1iL[c]; bb = bn1bL[c];
      }
      __syncthreads();
      bf16x8 af[4], bfr[4];
#pragma unroll
      for (int ii = 0; ii < 4; ii++) {
        int R = wy * 64 + ii * 16 + l15;
        af[ii] = *(const bf16x8*)&Alds[cur][R * 40 + (((q + (R >> 3)) & 3) << 3)];
      }
#pragma unroll
      for (int j = 0; j < 4; j++) {
        int R = wx * 64 + j * 16 + l15;
        bfr[j] = *(const bf16x8*)&Blds[cur][R * 40 + (((q + (R >> 3)) & 3) << 3)];
      }
#pragma unroll
      for (int ii = 0; ii < 4; ii++)
#pragma unroll
        for (int j = 0; j < 4; j++)
          acc[ii][j] = __builtin_amdgcn_mfma_f32_16x16x32_bf16(af[ii], bfr[j], acc[ii][j], 0, 0, 0);
    }

    // epilogue: bn2 + relu, store raw h2 NHWC bf16, per-block min/max partial
    float lmn = 3.4e38f, lmx = 0.0f;
#pragma unroll
    for (int i = 0; i < 4; i++) {
      int cob = wy * 64 + i * 16 + q * 4;
      f32x4 i2 = *(const f32x4*)&bn2iL[cob];
      f32x4 b2 = *(const f32x4*)&bn2bL[cob];
#pragma unroll
      for (int j = 0; j < 4; j++) {
        int sp = sp0 + wx * 64 + j * 16 + l15;
        u16x4 v;
#pragma unroll
        for (int r = 0; r < 4; r++) {
          float h = fmaxf(fmaf(acc[i][j][r], i2[r], b2[r]), 0.0f);
          v[r] = f2bf(h);
          lmn = fminf(lmn, h); lmx = fmaxf(lmx, h);
        }
        *(u16x4*)&h2[sp * C2 + cob] = v;
      }
    }
    for (int m = 32; m; m >>= 1) {
      lmn = fminf(lmn, __shfl_xor(lmn, m));
      lmx = fmaxf(lmx, __shfl_xor(lmx, m));
    }
    if (lane == 0) { wred[wv] = lmn; wred[4 + wv] = lmx; }
    __syncthreads();
    if (t == 0) {
      float2 pr;
      pr.x = fminf(fminf(wred[0], wred[1]), fminf(wred[2], wred[3]));
      pr.y = fmaxf(fmaxf(wred[4], wred[5]), fmaxf(wred[6], wred[7]));
      p2[bid] = pr;
    }
  }

  grid_barrier(bar, 2 * GRID);

  // ------------------------------ phase 2: conv2 --------------------------
  {
    // preamble: reduce 392 conv1-partials
    {
      float mn = 3.4e38f, mx = 0.0f;
      for (int i = t; i < CONV1_BLOCKS; i += 256) {
        float2 p = p2[i];
        mn = fminf(mn, p.x); mx = fmaxf(mx, p.y);
      }
      block_minmax(mn, mx);
      if (t == 0) { bc[0] = mn; bc[1] = mx; }
      __syncthreads();
    }
    const float mn2 = bc[0];
    const float s2 = fmaxf((bc[1] - mn2) / 255.0f, 1e-8f);
    const float r2 = 1.0f / s2;

    const int lane = t & 63;
    const int l15 = lane & 15;
    const int q = lane >> 4;
    const int wv = t >> 6;

    bf16x8 bz;
#pragma unroll
    for (int j = 0; j < 8; j++) bz[j] = 0;

    for (int job = bid; job < CONV2_JOBS; job += GRID) {
      const int sblk = (job & 7) * 98 + (job >> 3);  // XCD-contiguous sp map
      const int spf = sblk * 64 + wv * 16 + l15;
      const int nn = spf / HW;
      const int hwf = spf % HW;
      const int hf = hwf / WW;
      const int wf = hwf % WW;

      f32x4 acc[2] = {};

      for (int tap = 0; tap < 9; tap++) {
        const int dh = tap / 3 - 1, dw = tap % 3 - 1;
        const u16* wA = wq2 + tap * (C3 * C2);
        unsigned h2i = (unsigned)(hf + dh);
        unsigned w2i = (unsigned)(wf + dw);
        const bool val = (h2i < 28u) && (w2i < 28u);
        const u16* bptr = h2 + ((size_t)(nn * HW + (int)h2i * WW + (int)w2i)) * C2;
#pragma unroll
        for (int ks = 0; ks < C2; ks += 32) {
          bf16x8 a[2], b;
#pragma unroll
          for (int f = 0; f < 2; f++)
            a[f] = *(const bf16x8*)(wA + (f * 16 + l15) * C2 + ks + q * 8);
          if (val) {
            u16x8 hv = *(const u16x8*)(bptr + ks + q * 8);
#pragma unroll
            for (int j = 0; j < 8; j++) {
              float h = bf2f(hv[j]);
              b[j] = (short)f2bf(fmaf(rintf((h - mn2) * r2), s2, mn2));
            }
          } else {
            b = bz;
          }
#pragma unroll
          for (int i = 0; i < 2; i++)
            acc[i] = __builtin_amdgcn_mfma_f32_16x16x32_bf16(a[i], b, acc[i], 0, 0, 0);
        }
      }

#pragma unroll
      for (int i = 0; i < 2; i++) {
        int co = i * 16 + q * 4;
#pragma unroll
        for (int r = 0; r < 4; r++)
          out[(nn * C3 + co + r) * HW + hwf] = acc[i][r];
      }
    }
  }
}

// ---------------------------------------------------------------------------
extern "C" void kernel_launch(void* const* d_in, const int* in_sizes, int n_in,
                              void* d_out, int out_size, void* d_ws, size_t ws_size,
                              hipStream_t stream) {
  const float* x  = (const float*)d_in[0];
  const float* g1 = (const float*)d_in[1];
  const float* b1 = (const float*)d_in[2];
  const float* m1 = (const float*)d_in[3];
  const float* v1 = (const float*)d_in[4];
  const float* w1 = (const float*)d_in[5];
  const float* g2 = (const float*)d_in[6];
  const float* b2 = (const float*)d_in[7];
  const float* m2 = (const float*)d_in[8];
  const float* v2 = (const float*)d_in[9];
  const float* w2 = (const float*)d_in[10];
  unsigned char* ws = (unsigned char*)d_ws;
  float* out = (float*)d_out;

  bar_init_kernel<<<1, 64, 0, stream>>>(ws);
  fused_kernel<<<GRID, 256, 0, stream>>>(x, g1, b1, m1, v1, w1, g2, b2, m2, v2,
                                         w2, ws, out);
}

// Round 5
// 334.981 us; speedup vs baseline: 1.7642x; 1.7642x over previous
//
#include <hip/hip_runtime.h>

typedef unsigned short u16;
typedef unsigned short u16x4 __attribute__((ext_vector_type(4)));
typedef unsigned short u16x8 __attribute__((ext_vector_type(8)));
typedef short bf16x8 __attribute__((ext_vector_type(8)));
typedef float f32x4 __attribute__((ext_vector_type(4)));

#define EPSF 1e-5f

// Geometry
#define C1   512
#define C2   128
#define C3   32
#define HH   28
#define WW   28
#define HW   784            // 28*28
#define NHW  50176          // 64*784
#define XELEMS 25690112     // 64*512*784
#define NGROUPS 6422528     // XELEMS/4

#define GRID 512            // 2 blocks/CU, resident by construction
#define XBLOCKS 510
#define W1_BLOCK 510
#define W2_BLOCK 511
#define CONV1_BLOCKS 392    // NHW/128
#define CONV2_JOBS 784      // NHW/64

// ws layout (bytes)
#define WS_WQ1    5376      // 128*512 bf16   -> ends 136448
#define WS_WQ2    136448    // 9*32*128 bf16  -> ends 210176
#define WS_P1     210176    // 510 float2 partials (x scan)
#define WS_P2     226560    // 392 float2 partials (conv1) -> ends 229696
#define WS_BAR    229696    // grid-barrier counter (zeroed by init kernel)
#define WS_H2     233472    // 50176*128 bf16 (NHWC)

__device__ __forceinline__ float bf2f(u16 u) { return __uint_as_float(((unsigned)u) << 16); }
__device__ __forceinline__ u16 f2bf(float f) {
  unsigned x = __float_as_uint(f);
  return (u16)((x + 0x7fffu + ((x >> 16) & 1u)) >> 16);
}
__device__ __forceinline__ float finz(float f) {
  unsigned u = __float_as_uint(f);
  return ((u & 0x7f800000u) == 0x7f800000u) ? 0.0f : f;
}

// block-level min/max reduce; result valid on threadIdx.x==0
__device__ __forceinline__ void block_minmax(float& mn, float& mx) {
  for (int m = 32; m; m >>= 1) {
    mn = fminf(mn, __shfl_xor(mn, m));
    mx = fmaxf(mx, __shfl_xor(mx, m));
  }
  __shared__ float wmn[4], wmx[4];
  const int wv = threadIdx.x >> 6;
  if ((threadIdx.x & 63) == 0) { wmn[wv] = mn; wmx[wv] = mx; }
  __syncthreads();
  if (threadIdx.x == 0) {
    mn = fminf(fminf(wmn[0], wmn[1]), fminf(wmn[2], wmn[3]));
    mx = fmaxf(fmaxf(wmx[0], wmx[1]), fmaxf(wmx[2], wmx[3]));
  }
}

// Software grid barrier, cache-friendly version.
// R4 post-mortem: the previous version spun on an ACQUIRE atomic load --
// on gfx950 each agent-scope acquire load emits a buffer_inv (L1+L2
// invalidate) EVERY poll, so spinning blocks continuously wiped the XCD
// L2s while other blocks worked -> everything became a latency-bound
// L2/L3 miss (473us, 290 GB/s, all pipes idle).
// Now: RELAXED spin (no invalidation) + s_sleep backoff; ONE release RMW
// per block (syncthreads has already drained all waves' stores to L2;
// the RMW's L2 writeback makes them device-visible); ONE acquire load
// per block after the spin (single buffer_inv covers the CU's L1 and the
// XCD's stale L2 lines), then syncthreads orders the whole block.
__device__ __forceinline__ void grid_barrier(unsigned* bar, unsigned target) {
  __syncthreads();
  if (threadIdx.x == 0) {
    __hip_atomic_fetch_add(bar, 1u, __ATOMIC_RELEASE, __HIP_MEMORY_SCOPE_AGENT);
    while (__hip_atomic_load(bar, __ATOMIC_RELAXED, __HIP_MEMORY_SCOPE_AGENT) < target) {
      __builtin_amdgcn_s_sleep(4);
    }
    (void)__hip_atomic_load(bar, __ATOMIC_ACQUIRE, __HIP_MEMORY_SCOPE_AGENT);
  }
  __syncthreads();
}

__global__ void bar_init_kernel(unsigned char* ws) {
  if (threadIdx.x == 0) {
    __hip_atomic_store((unsigned*)(ws + WS_BAR), 0u, __ATOMIC_RELEASE,
                       __HIP_MEMORY_SCOPE_AGENT);
  }
}

// ---------------------------------------------------------------------------
// One fused kernel (plain launch + software grid barrier):
//  phase 0: blocks 0..509  -> min/max of relu(bn1(x))   (BN tables in LDS)
//           block 510      -> w1 minmax + quantize (single block, hidden)
//           block 511      -> w2 minmax + quantize+pack (single block, hidden)
//  barrier (512)
//  phase 1: blocks 0..391  -> conv1 128x128 MFMA tile (double-buffered LDS)
//  barrier (1024)
//  phase 2: all blocks     -> conv2 jobs (784 over 512, XCD-swizzled)
// ---------------------------------------------------------------------------
__global__ __launch_bounds__(256, 2) void fused_kernel(
    const float* __restrict__ x, const float* g1, const float* be1,
    const float* m1, const float* v1, const float* w1,
    const float* g2, const float* be2, const float* m2, const float* v2,
    const float* w2, unsigned char* ws, float* __restrict__ out) {
  __shared__ __align__(16) u16 Alds[2][128 * 40];
  __shared__ __align__(16) u16 Blds[2][128 * 40];
  __shared__ float bn1iL[C1], bn1bL[C1];
  __shared__ float bn2iL[C2], bn2bL[C2];
  __shared__ float bc[2];
  __shared__ float wred[8];

  const int t = threadIdx.x;
  const int bid = blockIdx.x;

  float2* p1 = (float2*)(ws + WS_P1);
  float2* p2 = (float2*)(ws + WS_P2);
  u16* wq1 = (u16*)(ws + WS_WQ1);
  u16* wq2 = (u16*)(ws + WS_WQ2);
  u16* h2 = (u16*)(ws + WS_H2);
  unsigned* bar = (unsigned*)(ws + WS_BAR);

  // per-block BN tables in LDS
  for (int c = t; c < C1; c += 256) {
    float inv = g1[c] / sqrtf(v1[c] + EPSF);
    bn1iL[c] = inv;
    bn1bL[c] = be1[c] - m1[c] * inv;
  }
  if (t < C2) {
    float inv = g2[t] / sqrtf(v2[t] + EPSF);
    bn2iL[t] = inv;
    bn2bL[t] = be2[t] - m2[t] * inv;
  }
  __syncthreads();

  // ------------------------------ phase 0 ---------------------------------
  if (bid < XBLOCKS) {
    const f32x4* x4 = (const f32x4*)x;
    float mn = 3.4e38f, mx = 0.0f;
    auto proc = [&](f32x4 u, int c) {
      float inv = bn1iL[c], bb = bn1bL[c];
#pragma unroll
      for (int j = 0; j < 4; j++) {
        float f = fmaxf(fmaf(u[j], inv, bb), 0.0f);
        mn = fminf(mn, f); mx = fmaxf(mx, f);
      }
    };
    const int S = XBLOCKS * 256;
    int i = bid * 256 + t;
    for (; i + 3 * S < NGROUPS; i += 4 * S) {
      f32x4 u0 = x4[i];
      f32x4 u1 = x4[i + S];
      f32x4 u2 = x4[i + 2 * S];
      f32x4 u3 = x4[i + 3 * S];
      int c0 = (i / 196) & (C1 - 1);
      int c1 = ((i + S) / 196) & (C1 - 1);
      int c2 = ((i + 2 * S) / 196) & (C1 - 1);
      int c3 = ((i + 3 * S) / 196) & (C1 - 1);
      proc(u0, c0); proc(u1, c1); proc(u2, c2); proc(u3, c3);
    }
    for (; i < NGROUPS; i += S) {
      f32x4 u = x4[i];
      proc(u, (i / 196) & (C1 - 1));
    }
    block_minmax(mn, mx);
    if (t == 0) p1[bid] = make_float2(mn, mx);
  } else if (bid == W1_BLOCK) {
    // whole w1 (128x512 f32) in one block: minmax, then quantize
    const f32x4* w4 = (const f32x4*)w1;
    float mn = 3.4e38f, mx = -3.4e38f;
#pragma unroll 8
    for (int k = t; k < 16384; k += 256) {
      f32x4 v = w4[k];
#pragma unroll
      for (int j = 0; j < 4; j++) {
        float f = finz(v[j]); mn = fminf(mn, f); mx = fmaxf(mx, f);
      }
    }
    block_minmax(mn, mx);
    if (t == 0) { bc[0] = mn; bc[1] = mx; }
    __syncthreads();
    const float mnv = bc[0];
    const float s = fmaxf((bc[1] - mnv) / 255.0f, 1e-8f);
    const float rs = 1.0f / s;
#pragma unroll 4
    for (int k = t; k < 16384; k += 256) {
      f32x4 v = w4[k];
      u16x4 o;
#pragma unroll
      for (int j = 0; j < 4; j++)
        o[j] = f2bf(fmaf(rintf((finz(v[j]) - mnv) * rs), s, mnv));
      *(u16x4*)(wq1 + k * 4) = o;
    }
  } else {
    // whole w2 (32x128x3x3 f32) in one block: minmax, quant+pack
    const f32x4* w4 = (const f32x4*)w2;
    float mn = 3.4e38f, mx = -3.4e38f;
#pragma unroll 4
    for (int k = t; k < 9216; k += 256) {
      f32x4 v = w4[k];
#pragma unroll
      for (int j = 0; j < 4; j++) {
        float f = finz(v[j]); mn = fminf(mn, f); mx = fmaxf(mx, f);
      }
    }
    block_minmax(mn, mx);
    if (t == 0) { bc[0] = mn; bc[1] = mx; }
    __syncthreads();
    const float mnv = bc[0];
    const float s = fmaxf((bc[1] - mnv) / 255.0f, 1e-8f);
    const float rs = 1.0f / s;
    // wq2 layout: tap*4096 + co*128 + ci  <- w2[(co*128+ci)*9 + tap]
    for (int jj = t; jj < 36864; jj += 256) {
      int tap = jj >> 12;
      int rem = jj & 4095;
      float f = finz(w2[rem * 9 + tap]);
      wq2[jj] = f2bf(fmaf(rintf((f - mnv) * rs), s, mnv));
    }
  }

  grid_barrier(bar, GRID);

  // ------------------------------ phase 1: conv1 --------------------------
  if (bid < CONV1_BLOCKS) {
    const int sp0 = bid * 128;

    // preamble: reduce 510 x-minmax partials
    {
      float mn = 3.4e38f, mx = 0.0f;
      for (int i = t; i < XBLOCKS; i += 256) {
        float2 p = p1[i];
        mn = fminf(mn, p.x); mx = fmaxf(mx, p.y);
      }
      block_minmax(mn, mx);
      if (t == 0) { bc[0] = mn; bc[1] = mx; }
      __syncthreads();
    }
    const float mn1 = bc[0];
    const float s1 = fmaxf((bc[1] - mn1) / 255.0f, 1e-8f);
    const float r1 = 1.0f / s1;

    // x staging: thread -> k-row kk (0..31), sp groups of 8 in both halves
    const int kk = t >> 3;
    const int spA = (t & 7) * 8;
    const int spB = 64 + spA;
    const int ga = sp0 + spA, gb = sp0 + spB;
    const int na = ga / HW, hwa = ga % HW;
    const int nb = gb / HW, hwb = gb % HW;
    const float* xA = x + na * (C1 * HW) + hwa;
    const float* xB = x + nb * (C1 * HW) + hwb;
    const int colg = (kk & 7) + 8 * ((((kk >> 3) + (spA >> 3))) & 3);

    // wq1 staging: thread -> co = t>>1, k offset (t&1)*16
    const int wco = t >> 1;
    const int wko = (t & 1) * 16;
    const int ab0 = wko >> 3;
    const int aswz = (wco >> 3) & 3;

    const int lane = t & 63;
    const int l15 = lane & 15;
    const int q = lane >> 4;
    const int wv = t >> 6;
    const int wy = wv >> 1;
    const int wx = wv & 1;

    f32x4 acc[4][4] = {};

    // prologue: load k=0 slice into registers
    u16x8 a0 = *(const u16x8*)(wq1 + wco * C1 + wko);
    u16x8 a1 = *(const u16x8*)(wq1 + wco * C1 + wko + 8);
    f32x4 va0 = *(const f32x4*)(xA + kk * HW);
    f32x4 va1 = *(const f32x4*)(xA + kk * HW + 4);
    f32x4 vb0 = *(const f32x4*)(xB + kk * HW);
    f32x4 vb1 = *(const f32x4*)(xB + kk * HW + 4);
    float inv = bn1iL[kk], bb = bn1bL[kk];

#pragma unroll 1
    for (int i = 0; i < 16; i++) {
      const int cur = i & 1;
      *(u16x8*)&Alds[cur][wco * 40 + (((ab0 + 0 + aswz) & 3) << 3)] = a0;
      *(u16x8*)&Alds[cur][wco * 40 + (((ab0 + 1 + aswz) & 3) << 3)] = a1;
#pragma unroll
      for (int j = 0; j < 4; j++) {
        float f0 = fmaxf(fmaf(va0[j], inv, bb), 0.0f);
        Blds[cur][(spA + j) * 40 + colg] = f2bf(fmaf(rintf((f0 - mn1) * r1), s1, mn1));
        float f1 = fmaxf(fmaf(va1[j], inv, bb), 0.0f);
        Blds[cur][(spA + 4 + j) * 40 + colg] = f2bf(fmaf(rintf((f1 - mn1) * r1), s1, mn1));
        float g0 = fmaxf(fmaf(vb0[j], inv, bb), 0.0f);
        Blds[cur][(spB + j) * 40 + colg] = f2bf(fmaf(rintf((g0 - mn1) * r1), s1, mn1));
        float g1v = fmaxf(fmaf(vb1[j], inv, bb), 0.0f);
        Blds[cur][(spB + 4 + j) * 40 + colg] = f2bf(fmaf(rintf((g1v - mn1) * r1), s1, mn1));
      }
      if (i < 15) {
        const int kn = (i + 1) * 32;
        a0 = *(const u16x8*)(wq1 + wco * C1 + kn + wko);
        a1 = *(const u16x8*)(wq1 + wco * C1 + kn + wko + 8);
        const int c = kn + kk;
        va0 = *(const f32x4*)(xA + c * HW);
        va1 = *(const f32x4*)(xA + c * HW + 4);
        vb0 = *(const f32x4*)(xB + c * HW);
        vb1 = *(const f32x4*)(xB + c * HW + 4);
        inv = bn1iL[c]; bb = bn1bL[c];
      }
      __syncthreads();
      bf16x8 af[4], bfr[4];
#pragma unroll
      for (int ii = 0; ii < 4; ii++) {
        int R = wy * 64 + ii * 16 + l15;
        af[ii] = *(const bf16x8*)&Alds[cur][R * 40 + (((q + (R >> 3)) & 3) << 3)];
      }
#pragma unroll
      for (int j = 0; j < 4; j++) {
        int R = wx * 64 + j * 16 + l15;
        bfr[j] = *(const bf16x8*)&Blds[cur][R * 40 + (((q + (R >> 3)) & 3) << 3)];
      }
#pragma unroll
      for (int ii = 0; ii < 4; ii++)
#pragma unroll
        for (int j = 0; j < 4; j++)
          acc[ii][j] = __builtin_amdgcn_mfma_f32_16x16x32_bf16(af[ii], bfr[j], acc[ii][j], 0, 0, 0);
    }

    // epilogue: bn2 + relu, store raw h2 NHWC bf16, per-block min/max partial
    float lmn = 3.4e38f, lmx = 0.0f;
#pragma unroll
    for (int i = 0; i < 4; i++) {
      int cob = wy * 64 + i * 16 + q * 4;
      f32x4 i2 = *(const f32x4*)&bn2iL[cob];
      f32x4 b2 = *(const f32x4*)&bn2bL[cob];
#pragma unroll
      for (int j = 0; j < 4; j++) {
        int sp = sp0 + wx * 64 + j * 16 + l15;
        u16x4 v;
#pragma unroll
        for (int r = 0; r < 4; r++) {
          float h = fmaxf(fmaf(acc[i][j][r], i2[r], b2[r]), 0.0f);
          v[r] = f2bf(h);
          lmn = fminf(lmn, h); lmx = fmaxf(lmx, h);
        }
        *(u16x4*)&h2[sp * C2 + cob] = v;
      }
    }
    for (int m = 32; m; m >>= 1) {
      lmn = fminf(lmn, __shfl_xor(lmn, m));
      lmx = fmaxf(lmx, __shfl_xor(lmx, m));
    }
    if (lane == 0) { wred[wv] = lmn; wred[4 + wv] = lmx; }
    __syncthreads();
    if (t == 0) {
      float2 pr;
      pr.x = fminf(fminf(wred[0], wred[1]), fminf(wred[2], wred[3]));
      pr.y = fmaxf(fmaxf(wred[4], wred[5]), fmaxf(wred[6], wred[7]));
      p2[bid] = pr;
    }
  }

  grid_barrier(bar, 2 * GRID);

  // ------------------------------ phase 2: conv2 --------------------------
  {
    // preamble: reduce 392 conv1-partials
    {
      float mn = 3.4e38f, mx = 0.0f;
      for (int i = t; i < CONV1_BLOCKS; i += 256) {
        float2 p = p2[i];
        mn = fminf(mn, p.x); mx = fmaxf(mx, p.y);
      }
      block_minmax(mn, mx);
      if (t == 0) { bc[0] = mn; bc[1] = mx; }
      __syncthreads();
    }
    const float mn2 = bc[0];
    const float s2 = fmaxf((bc[1] - mn2) / 255.0f, 1e-8f);
    const float r2 = 1.0f / s2;

    const int lane = t & 63;
    const int l15 = lane & 15;
    const int q = lane >> 4;
    const int wv = t >> 6;

    bf16x8 bz;
#pragma unroll
    for (int j = 0; j < 8; j++) bz[j] = 0;

    for (int job = bid; job < CONV2_JOBS; job += GRID) {
      const int sblk = (job & 7) * 98 + (job >> 3);  // XCD-contiguous sp map
      const int spf = sblk * 64 + wv * 16 + l15;
      const int nn = spf / HW;
      const int hwf = spf % HW;
      const int hf = hwf / WW;
      const int wf = hwf % WW;

      f32x4 acc[2] = {};

      for (int tap = 0; tap < 9; tap++) {
        const int dh = tap / 3 - 1, dw = tap % 3 - 1;
        const u16* wA = wq2 + tap * (C3 * C2);
        unsigned h2i = (unsigned)(hf + dh);
        unsigned w2i = (unsigned)(wf + dw);
        const bool val = (h2i < 28u) && (w2i < 28u);
        const u16* bptr = h2 + ((size_t)(nn * HW + (int)h2i * WW + (int)w2i)) * C2;
#pragma unroll
        for (int ks = 0; ks < C2; ks += 32) {
          bf16x8 a[2], b;
#pragma unroll
          for (int f = 0; f < 2; f++)
            a[f] = *(const bf16x8*)(wA + (f * 16 + l15) * C2 + ks + q * 8);
          if (val) {
            u16x8 hv = *(const u16x8*)(bptr + ks + q * 8);
#pragma unroll
            for (int j = 0; j < 8; j++) {
              float h = bf2f(hv[j]);
              b[j] = (short)f2bf(fmaf(rintf((h - mn2) * r2), s2, mn2));
            }
          } else {
            b = bz;
          }
#pragma unroll
          for (int i = 0; i < 2; i++)
            acc[i] = __builtin_amdgcn_mfma_f32_16x16x32_bf16(a[i], b, acc[i], 0, 0, 0);
        }
      }

#pragma unroll
      for (int i = 0; i < 2; i++) {
        int co = i * 16 + q * 4;
#pragma unroll
        for (int r = 0; r < 4; r++)
          out[(nn * C3 + co + r) * HW + hwf] = acc[i][r];
      }
    }
  }
}

// ---------------------------------------------------------------------------
extern "C" void kernel_launch(void* const* d_in, const int* in_sizes, int n_in,
                              void* d_out, int out_size, void* d_ws, size_t ws_size,
                              hipStream_t stream) {
  const float* x  = (const float*)d_in[0];
  const float* g1 = (const float*)d_in[1];
  const float* b1 = (const float*)d_in[2];
  const float* m1 = (const float*)d_in[3];
  const float* v1 = (const float*)d_in[4];
  const float* w1 = (const float*)d_in[5];
  const float* g2 = (const float*)d_in[6];
  const float* b2 = (const float*)d_in[7];
  const float* m2 = (const float*)d_in[8];
  const float* v2 = (const float*)d_in[9];
  const float* w2 = (const float*)d_in[10];
  unsigned char* ws = (unsigned char*)d_ws;
  float* out = (float*)d_out;

  bar_init_kernel<<<1, 64, 0, stream>>>(ws);
  fused_kernel<<<GRID, 256, 0, stream>>>(x, g1, b1, m1, v1, w1, g2, b2, m2, v2,
                                         w2, ws, out);
}

// Round 7
// 263.876 us; speedup vs baseline: 2.2396x; 1.2695x over previous
//
#include <hip/hip_runtime.h>

typedef unsigned short u16;
typedef unsigned short u16x4 __attribute__((ext_vector_type(4)));
typedef unsigned short u16x8 __attribute__((ext_vector_type(8)));
typedef short bf16x8 __attribute__((ext_vector_type(8)));
typedef float f32x4 __attribute__((ext_vector_type(4)));

#define EPSF 1e-5f

// Geometry
#define C1   512
#define C2   128
#define C3   32
#define HH   28
#define WW   28
#define HW   784            // 28*28
#define NHW  50176          // 64*784
#define XELEMS 25690112     // 64*512*784
#define NGROUPS 6422528     // XELEMS/4

#define K1_BLOCKS 2048      // scan blocks (full-occupancy grid)
#define K1_GRID   2050      // + w1 block + w2 block
#define CONV1_BLOCKS 392    // NHW/128
#define CONV2_BLOCKS 784    // NHW/64

// ws layout (bytes)
#define WS_WQ1    5376      // 128*512 bf16   -> ends 136448
#define WS_WQ2    136448    // 9*32*128 bf16  -> ends 210176
#define WS_P1     210176    // 2048 float2 partials (x scan) -> ends 226560
#define WS_P2     226560    // 392 float2 partials (conv1)   -> ends 229696
#define WS_H2     233472    // 50176*128 bf16 (NHWC)

__device__ __forceinline__ float bf2f(u16 u) { return __uint_as_float(((unsigned)u) << 16); }
__device__ __forceinline__ u16 f2bf(float f) {
  unsigned x = __float_as_uint(f);
  return (u16)((x + 0x7fffu + ((x >> 16) & 1u)) >> 16);
}
__device__ __forceinline__ float finz(float f) {
  unsigned u = __float_as_uint(f);
  return ((u & 0x7f800000u) == 0x7f800000u) ? 0.0f : f;
}

// block-level min/max reduce; result valid on threadIdx.x==0
__device__ __forceinline__ void block_minmax(float& mn, float& mx) {
  for (int m = 32; m; m >>= 1) {
    mn = fminf(mn, __shfl_xor(mn, m));
    mx = fmaxf(mx, __shfl_xor(mx, m));
  }
  __shared__ float wmn[4], wmx[4];
  const int wv = threadIdx.x >> 6;
  if ((threadIdx.x & 63) == 0) { wmn[wv] = mn; wmx[wv] = mx; }
  __syncthreads();
  if (threadIdx.x == 0) {
    mn = fminf(fminf(wmn[0], wmn[1]), fminf(wmn[2], wmn[3]));
    mx = fmaxf(fmaxf(wmx[0], wmx[1]), fmaxf(wmx[2], wmx[3]));
  }
}

// ---------------------------------------------------------------------------
// kA: blocks 0..2047 -> min/max of relu(bn1(x)) at full occupancy.
//     block 2048     -> w1 minmax + quantize (one block, hidden under scan)
//     block 2049     -> w2 minmax + quantize+pack (one block, hidden)
// Replaces the old kwA/kwB/k1 trio (removes 2 dispatches + dependency gaps).
// ---------------------------------------------------------------------------
__global__ __launch_bounds__(256) void kA_kernel(
    const float* __restrict__ x, const float* g1, const float* be1,
    const float* m1, const float* v1, const float* w1, const float* w2,
    unsigned char* ws) {
  const int t = threadIdx.x;
  const int bid = blockIdx.x;
  float2* p1 = (float2*)(ws + WS_P1);
  u16* wq1 = (u16*)(ws + WS_WQ1);
  u16* wq2 = (u16*)(ws + WS_WQ2);
  __shared__ float bc[2];
  __shared__ float bn1iL[C1], bn1bL[C1];

  if (bid < K1_BLOCKS) {
    // per-block BN1 tables in LDS (from globals; 8KB of L2-hot reads)
    for (int c = t; c < C1; c += 256) {
      float inv = g1[c] / sqrtf(v1[c] + EPSF);
      bn1iL[c] = inv;
      bn1bL[c] = be1[c] - m1[c] * inv;
    }
    __syncthreads();

    const f32x4* x4 = (const f32x4*)x;
    float mn = 3.4e38f, mx = 0.0f;
    auto proc = [&](f32x4 u, int c) {
      float inv = bn1iL[c], bb = bn1bL[c];
#pragma unroll
      for (int j = 0; j < 4; j++) {
        float f = fmaxf(fmaf(u[j], inv, bb), 0.0f);
        mn = fminf(mn, f); mx = fmaxf(mx, f);
      }
    };
    const int S = K1_BLOCKS * 256;
    int i = bid * 256 + t;
    for (; i + 3 * S < NGROUPS; i += 4 * S) {
      f32x4 u0 = x4[i];
      f32x4 u1 = x4[i + S];
      f32x4 u2 = x4[i + 2 * S];
      f32x4 u3 = x4[i + 3 * S];
      int c0 = (i / 196) & (C1 - 1);
      int c1 = ((i + S) / 196) & (C1 - 1);
      int c2 = ((i + 2 * S) / 196) & (C1 - 1);
      int c3 = ((i + 3 * S) / 196) & (C1 - 1);
      proc(u0, c0); proc(u1, c1); proc(u2, c2); proc(u3, c3);
    }
    for (; i < NGROUPS; i += S) {
      f32x4 u = x4[i];
      proc(u, (i / 196) & (C1 - 1));
    }
    block_minmax(mn, mx);
    if (t == 0) p1[bid] = make_float2(mn, mx);
  } else if (bid == K1_BLOCKS) {
    // whole w1 (128x512 f32) in one block: minmax, then quantize
    const f32x4* w4 = (const f32x4*)w1;
    float mn = 3.4e38f, mx = -3.4e38f;
#pragma unroll 8
    for (int k = t; k < 16384; k += 256) {
      f32x4 v = w4[k];
#pragma unroll
      for (int j = 0; j < 4; j++) {
        float f = finz(v[j]); mn = fminf(mn, f); mx = fmaxf(mx, f);
      }
    }
    block_minmax(mn, mx);
    if (t == 0) { bc[0] = mn; bc[1] = mx; }
    __syncthreads();
    const float mnv = bc[0];
    const float s = fmaxf((bc[1] - mnv) / 255.0f, 1e-8f);
    const float rs = 1.0f / s;
#pragma unroll 4
    for (int k = t; k < 16384; k += 256) {
      f32x4 v = w4[k];
      u16x4 o;
#pragma unroll
      for (int j = 0; j < 4; j++)
        o[j] = f2bf(fmaf(rintf((finz(v[j]) - mnv) * rs), s, mnv));
      *(u16x4*)(wq1 + k * 4) = o;
    }
  } else {
    // whole w2 (32x128x3x3 f32) in one block: minmax, quant+pack
    const f32x4* w4 = (const f32x4*)w2;
    float mn = 3.4e38f, mx = -3.4e38f;
#pragma unroll 4
    for (int k = t; k < 9216; k += 256) {
      f32x4 v = w4[k];
#pragma unroll
      for (int j = 0; j < 4; j++) {
        float f = finz(v[j]); mn = fminf(mn, f); mx = fmaxf(mx, f);
      }
    }
    block_minmax(mn, mx);
    if (t == 0) { bc[0] = mn; bc[1] = mx; }
    __syncthreads();
    const float mnv = bc[0];
    const float s = fmaxf((bc[1] - mnv) / 255.0f, 1e-8f);
    const float rs = 1.0f / s;
    // wq2 layout: tap*4096 + co*128 + ci  <- w2[(co*128+ci)*9 + tap]
    for (int jj = t; jj < 36864; jj += 256) {
      int tap = jj >> 12;
      int rem = jj & 4095;
      float f = finz(w2[rem * 9 + tap]);
      wq2[jj] = f2bf(fmaf(rintf((f - mnv) * rs), s, mnv));
    }
  }
}

// ---------------------------------------------------------------------------
// conv1: 1x1 conv MFMA GEMM, tile 128co x 128sp, double-buffered LDS,
// one barrier per K-iter; BN tables built per block in LDS.
// ---------------------------------------------------------------------------
__global__ __launch_bounds__(256) void conv1_kernel(
    const float* __restrict__ x, const float* g1, const float* be1,
    const float* m1, const float* v1, const float* g2, const float* be2,
    const float* m2, const float* v2, unsigned char* ws) {
  const float2* p1 = (const float2*)(ws + WS_P1);
  float2* p2 = (float2*)(ws + WS_P2);
  const u16* wq1 = (const u16*)(ws + WS_WQ1);
  u16* h2 = (u16*)(ws + WS_H2);

  __shared__ __align__(16) u16 Alds[2][128 * 40];
  __shared__ __align__(16) u16 Blds[2][128 * 40];
  __shared__ float bn1iL[C1], bn1bL[C1];
  __shared__ float bn2iL[C2], bn2bL[C2];
  __shared__ float bc[2];
  __shared__ float wred[8];

  const int t = threadIdx.x;
  const int sp0 = blockIdx.x * 128;

  // per-block BN tables in LDS
  for (int c = t; c < C1; c += 256) {
    float inv = g1[c] / sqrtf(v1[c] + EPSF);
    bn1iL[c] = inv;
    bn1bL[c] = be1[c] - m1[c] * inv;
  }
  if (t < C2) {
    float inv = g2[t] / sqrtf(v2[t] + EPSF);
    bn2iL[t] = inv;
    bn2bL[t] = be2[t] - m2[t] * inv;
  }

  // preamble: reduce 2048 scan partials (8 float2/thread)
  {
    float mn = 3.4e38f, mx = 0.0f;
    for (int i = t; i < K1_BLOCKS; i += 256) {
      float2 p = p1[i];
      mn = fminf(mn, p.x); mx = fmaxf(mx, p.y);
    }
    block_minmax(mn, mx);
    if (t == 0) { bc[0] = mn; bc[1] = mx; }
    __syncthreads();
  }
  const float mn1 = bc[0];
  const float s1 = fmaxf((bc[1] - mn1) / 255.0f, 1e-8f);
  const float r1 = 1.0f / s1;

  // x staging: thread -> k-row kk (0..31), sp groups of 8 in both halves
  const int kk = t >> 3;
  const int spA = (t & 7) * 8;
  const int spB = 64 + spA;
  const int ga = sp0 + spA, gb = sp0 + spB;
  const int na = ga / HW, hwa = ga % HW;
  const int nb = gb / HW, hwb = gb % HW;
  const float* xA = x + na * (C1 * HW) + hwa;
  const float* xB = x + nb * (C1 * HW) + hwb;
  const int colg = (kk & 7) + 8 * ((((kk >> 3) + (spA >> 3))) & 3);

  // wq1 staging: thread -> co = t>>1, k offset (t&1)*16
  const int wco = t >> 1;
  const int wko = (t & 1) * 16;
  const int ab0 = wko >> 3;
  const int aswz = (wco >> 3) & 3;

  const int lane = t & 63;
  const int l15 = lane & 15;
  const int q = lane >> 4;
  const int wv = t >> 6;
  const int wy = wv >> 1;
  const int wx = wv & 1;

  f32x4 acc[4][4] = {};

  // prologue: load k=0 slice into registers
  u16x8 a0 = *(const u16x8*)(wq1 + wco * C1 + wko);
  u16x8 a1 = *(const u16x8*)(wq1 + wco * C1 + wko + 8);
  f32x4 va0 = *(const f32x4*)(xA + kk * HW);
  f32x4 va1 = *(const f32x4*)(xA + kk * HW + 4);
  f32x4 vb0 = *(const f32x4*)(xB + kk * HW);
  f32x4 vb1 = *(const f32x4*)(xB + kk * HW + 4);
  float inv = bn1iL[kk], bb = bn1bL[kk];

#pragma unroll 1
  for (int i = 0; i < 16; i++) {
    const int cur = i & 1;
    *(u16x8*)&Alds[cur][wco * 40 + (((ab0 + 0 + aswz) & 3) << 3)] = a0;
    *(u16x8*)&Alds[cur][wco * 40 + (((ab0 + 1 + aswz) & 3) << 3)] = a1;
#pragma unroll
    for (int j = 0; j < 4; j++) {
      float f0 = fmaxf(fmaf(va0[j], inv, bb), 0.0f);
      Blds[cur][(spA + j) * 40 + colg] = f2bf(fmaf(rintf((f0 - mn1) * r1), s1, mn1));
      float f1 = fmaxf(fmaf(va1[j], inv, bb), 0.0f);
      Blds[cur][(spA + 4 + j) * 40 + colg] = f2bf(fmaf(rintf((f1 - mn1) * r1), s1, mn1));
      float g0 = fmaxf(fmaf(vb0[j], inv, bb), 0.0f);
      Blds[cur][(spB + j) * 40 + colg] = f2bf(fmaf(rintf((g0 - mn1) * r1), s1, mn1));
      float g1v = fmaxf(fmaf(vb1[j], inv, bb), 0.0f);
      Blds[cur][(spB + 4 + j) * 40 + colg] = f2bf(fmaf(rintf((g1v - mn1) * r1), s1, mn1));
    }
    if (i < 15) {
      const int kn = (i + 1) * 32;
      a0 = *(const u16x8*)(wq1 + wco * C1 + kn + wko);
      a1 = *(const u16x8*)(wq1 + wco * C1 + kn + wko + 8);
      const int c = kn + kk;
      va0 = *(const f32x4*)(xA + c * HW);
      va1 = *(const f32x4*)(xA + c * HW + 4);
      vb0 = *(const f32x4*)(xB + c * HW);
      vb1 = *(const f32x4*)(xB + c * HW + 4);
      inv = bn1iL[c]; bb = bn1bL[c];
    }
    __syncthreads();
    bf16x8 af[4], bfr[4];
#pragma unroll
    for (int ii = 0; ii < 4; ii++) {
      int R = wy * 64 + ii * 16 + l15;
      af[ii] = *(const bf16x8*)&Alds[cur][R * 40 + (((q + (R >> 3)) & 3) << 3)];
    }
#pragma unroll
    for (int j = 0; j < 4; j++) {
      int R = wx * 64 + j * 16 + l15;
      bfr[j] = *(const bf16x8*)&Blds[cur][R * 40 + (((q + (R >> 3)) & 3) << 3)];
    }
#pragma unroll
    for (int ii = 0; ii < 4; ii++)
#pragma unroll
      for (int j = 0; j < 4; j++)
        acc[ii][j] = __builtin_amdgcn_mfma_f32_16x16x32_bf16(af[ii], bfr[j], acc[ii][j], 0, 0, 0);
  }

  // epilogue: bn2 + relu, store raw h2 NHWC bf16, per-block min/max partial
  float lmn = 3.4e38f, lmx = 0.0f;
#pragma unroll
  for (int i = 0; i < 4; i++) {
    int cob = wy * 64 + i * 16 + q * 4;
    f32x4 i2 = *(const f32x4*)&bn2iL[cob];
    f32x4 b2 = *(const f32x4*)&bn2bL[cob];
#pragma unroll
    for (int j = 0; j < 4; j++) {
      int sp = sp0 + wx * 64 + j * 16 + l15;
      u16x4 v;
#pragma unroll
      for (int r = 0; r < 4; r++) {
        float h = fmaxf(fmaf(acc[i][j][r], i2[r], b2[r]), 0.0f);
        v[r] = f2bf(h);
        lmn = fminf(lmn, h); lmx = fmaxf(lmx, h);
      }
      *(u16x4*)&h2[sp * C2 + cob] = v;
    }
  }
  for (int m = 32; m; m >>= 1) {
    lmn = fminf(lmn, __shfl_xor(lmn, m));
    lmx = fmaxf(lmx, __shfl_xor(lmx, m));
  }
  if (lane == 0) { wred[wv] = lmn; wred[4 + wv] = lmx; }
  __syncthreads();
  if (t == 0) {
    float2 pr;
    pr.x = fminf(fminf(wred[0], wred[1]), fminf(wred[2], wred[3]));
    pr.y = fmaxf(fmaxf(wred[4], wred[5]), fmaxf(wred[6], wred[7]));
    p2[blockIdx.x] = pr;
  }
}

// ---------------------------------------------------------------------------
// conv2: 3x3 conv (pad 1) direct MFMA, inline h2 quant, XCD-aware swizzle.
// ---------------------------------------------------------------------------
__global__ __launch_bounds__(256) void conv2_kernel(const unsigned char* ws,
                                                    float* __restrict__ out) {
  const u16* wq2 = (const u16*)(ws + WS_WQ2);
  const u16* h2 = (const u16*)(ws + WS_H2);
  const float2* p2 = (const float2*)(ws + WS_P2);
  __shared__ float bc2[2];

  const int t = threadIdx.x;
  {  // preamble: reduce 392 conv1-partials
    float mn = 3.4e38f, mx = 0.0f;
    for (int i = t; i < CONV1_BLOCKS; i += 256) {
      float2 p = p2[i];
      mn = fminf(mn, p.x); mx = fmaxf(mx, p.y);
    }
    block_minmax(mn, mx);
    if (t == 0) { bc2[0] = mn; bc2[1] = mx; }
    __syncthreads();
  }
  const float mn2 = bc2[0];
  const float s2 = fmaxf((bc2[1] - mn2) / 255.0f, 1e-8f);
  const float r2 = 1.0f / s2;

  const int lane = t & 63;
  const int l15 = lane & 15;
  const int q = lane >> 4;
  const int wv = t >> 6;

  const int B = blockIdx.x;
  const int sblk = (B & 7) * 98 + (B >> 3);    // XCD-contiguous sp mapping
  const int spf = sblk * 64 + wv * 16 + l15;
  const int nn = spf / HW;
  const int hwf = spf % HW;
  const int hf = hwf / WW;
  const int wf = hwf % WW;

  f32x4 acc[2] = {};
  bf16x8 bz;
#pragma unroll
  for (int j = 0; j < 8; j++) bz[j] = 0;

  for (int tap = 0; tap < 9; tap++) {
    const int dh = tap / 3 - 1, dw = tap % 3 - 1;
    const u16* wA = wq2 + tap * (C3 * C2);
    unsigned h2i = (unsigned)(hf + dh);
    unsigned w2i = (unsigned)(wf + dw);
    const bool val = (h2i < 28u) && (w2i < 28u);
    const u16* bptr = h2 + ((size_t)(nn * HW + (int)h2i * WW + (int)w2i)) * C2;
#pragma unroll
    for (int ks = 0; ks < C2; ks += 32) {
      bf16x8 a[2], b;
#pragma unroll
      for (int f = 0; f < 2; f++)
        a[f] = *(const bf16x8*)(wA + (f * 16 + l15) * C2 + ks + q * 8);
      if (val) {
        u16x8 hv = *(const u16x8*)(bptr + ks + q * 8);
#pragma unroll
        for (int j = 0; j < 8; j++) {
          float h = bf2f(hv[j]);
          b[j] = (short)f2bf(fmaf(rintf((h - mn2) * r2), s2, mn2));
        }
      } else {
        b = bz;
      }
#pragma unroll
      for (int i = 0; i < 2; i++)
        acc[i] = __builtin_amdgcn_mfma_f32_16x16x32_bf16(a[i], b, acc[i], 0, 0, 0);
    }
  }

#pragma unroll
  for (int i = 0; i < 2; i++) {
    int co = i * 16 + q * 4;
#pragma unroll
    for (int r = 0; r < 4; r++)
      out[(nn * C3 + co + r) * HW + hwf] = acc[i][r];
  }
}

// ---------------------------------------------------------------------------
extern "C" void kernel_launch(void* const* d_in, const int* in_sizes, int n_in,
                              void* d_out, int out_size, void* d_ws, size_t ws_size,
                              hipStream_t stream) {
  const float* x  = (const float*)d_in[0];
  const float* g1 = (const float*)d_in[1];
  const float* b1 = (const float*)d_in[2];
  const float* m1 = (const float*)d_in[3];
  const float* v1 = (const float*)d_in[4];
  const float* w1 = (const float*)d_in[5];
  const float* g2 = (const float*)d_in[6];
  const float* b2 = (const float*)d_in[7];
  const float* m2 = (const float*)d_in[8];
  const float* v2 = (const float*)d_in[9];
  const float* w2 = (const float*)d_in[10];
  unsigned char* ws = (unsigned char*)d_ws;
  float* out = (float*)d_out;

  kA_kernel<<<K1_GRID, 256, 0, stream>>>(x, g1, b1, m1, v1, w1, w2, ws);
  conv1_kernel<<<CONV1_BLOCKS, 256, 0, stream>>>(x, g1, b1, m1, v1, g2, b2, m2, v2, ws);
  conv2_kernel<<<CONV2_BLOCKS, 256, 0, stream>>>(ws, out);
}

// Round 9
// 262.407 us; speedup vs baseline: 2.2522x; 1.0056x over previous
//
#include <hip/hip_runtime.h>

typedef unsigned short u16;
typedef unsigned short u16x4 __attribute__((ext_vector_type(4)));
typedef unsigned short u16x8 __attribute__((ext_vector_type(8)));
typedef short bf16x8 __attribute__((ext_vector_type(8)));
typedef float f32x4 __attribute__((ext_vector_type(4)));

#define EPSF 1e-5f

// Geometry
#define C1   512
#define C2   128
#define C3   32
#define HH   28
#define WW   28
#define HW   784            // 28*28
#define NHW  50176          // 64*784
#define XELEMS 25690112     // 64*512*784

#define SCAN_BLOCKS 1024    // (channel, batch-half) pairs: 512 x 2
#define KA_GRID     1027    // + w1 block + w2 block + bn-table block
#define CONV1_BLOCKS 392    // NHW/128
#define CONV2_BLOCKS 784    // NHW/64

// ws layout (bytes)
#define WS_BN1I   64        // 512 f32
#define WS_BN1B   2112      // 512 f32
#define WS_BN2I   4160      // 128 f32
#define WS_BN2B   4672      // 128 f32 -> ends 5184
#define WS_WQ1    5376      // 128*512 bf16   -> ends 136448
#define WS_WQ2    136448    // 9*32*128 bf16  -> ends 210176
#define WS_P1     210176    // 1024 float2 transformed channel partials -> ends 218368
#define WS_P2     226560    // 392 float2 partials (conv1) -> ends 229696
#define WS_H2     233472    // 50176*128 bf16 (NHWC)

__device__ __forceinline__ float bf2f(u16 u) { return __uint_as_float(((unsigned)u) << 16); }
__device__ __forceinline__ u16 f2bf(float f) {
  unsigned x = __float_as_uint(f);
  return (u16)((x + 0x7fffu + ((x >> 16) & 1u)) >> 16);
}
__device__ __forceinline__ float finz(float f) {
  unsigned u = __float_as_uint(f);
  return ((u & 0x7f800000u) == 0x7f800000u) ? 0.0f : f;
}

// block-level min/max reduce; result valid on threadIdx.x==0
__device__ __forceinline__ void block_minmax(float& mn, float& mx) {
  for (int m = 32; m; m >>= 1) {
    mn = fminf(mn, __shfl_xor(mn, m));
    mx = fmaxf(mx, __shfl_xor(mx, m));
  }
  __shared__ float wmn[4], wmx[4];
  const int wv = threadIdx.x >> 6;
  if ((threadIdx.x & 63) == 0) { wmn[wv] = mn; wmx[wv] = mx; }
  __syncthreads();
  if (threadIdx.x == 0) {
    mn = fminf(fminf(wmn[0], wmn[1]), fminf(wmn[2], wmn[3]));
    mx = fmaxf(fmaxf(wmx[0], wmx[1]), fmaxf(wmx[2], wmx[3]));
  }
}

// ---------------------------------------------------------------------------
// kA: blocks 0..1023 -> per-(channel, batch-half) RAW x min/max, then ONE
//     monotone bn+relu transform at block end (exact: inv>0 since gamma>0,
//     fma/relu rounding-monotone -> transform(min raw) == min(transformed)).
//     No BN table, no per-element channel math: pure coalesced streaming
//     with 4 independent accumulator pairs (R7 fix: old scan had only 3
//     latency-serialized iterations/thread behind a per-block BN build).
//     block 1024 -> w1 minmax+quantize; 1025 -> w2 minmax+quant+pack;
//     1026 -> bn1/bn2 tables for conv1/conv2 (restores verified baseline).
// ---------------------------------------------------------------------------
__global__ __launch_bounds__(256) void kA_kernel(
    const float* __restrict__ x, const float* g1, const float* be1,
    const float* m1, const float* v1, const float* w1,
    const float* g2, const float* be2, const float* m2, const float* v2,
    const float* w2, unsigned char* ws) {
  const int t = threadIdx.x;
  const int bid = blockIdx.x;
  float2* p1 = (float2*)(ws + WS_P1);
  u16* wq1 = (u16*)(ws + WS_WQ1);
  u16* wq2 = (u16*)(ws + WS_WQ2);
  __shared__ float bc[2];

  if (bid < SCAN_BLOCKS) {
    const int c = bid >> 1;
    const int n0 = (bid & 1) << 5;   // batch half: n in [n0, n0+32)
    // f32x4 base of (n0, c, 0); segment s (=n-n0) stride 512*196 groups
    const f32x4* xb = (const f32x4*)x + ((size_t)n0 * C1 + c) * 196;
    float mn0 = 3.4e38f, mx0 = -3.4e38f, mn1 = 3.4e38f, mx1 = -3.4e38f;
    float mn2 = 3.4e38f, mx2 = -3.4e38f, mn3 = 3.4e38f, mx3 = -3.4e38f;
    auto P = [&](int j, float& mn, float& mx) {
      int s = j / 196;               // segment (batch index offset)
      int g = j - s * 196;           // f32x4 column within row
      f32x4 v = xb[(size_t)s * (C1 * 196) + g];
      mn = fminf(mn, fminf(fminf(v[0], v[1]), fminf(v[2], v[3])));
      mx = fmaxf(mx, fmaxf(fmaxf(v[0], v[1]), fmaxf(v[2], v[3])));
    };
    // 6272 groups per block (32 rows x 196), strided by t: 24-25 per thread
    int j = t;
    for (; j + 768 < 6272; j += 1024) {
      P(j, mn0, mx0); P(j + 256, mn1, mx1);
      P(j + 512, mn2, mx2); P(j + 768, mn3, mx3);
    }
    for (; j < 6272; j += 256) P(j, mn0, mx0);
    float mn = fminf(fminf(mn0, mn1), fminf(mn2, mn3));
    float mx = fmaxf(fmaxf(mx0, mx1), fmaxf(mx2, mx3));
    block_minmax(mn, mx);
    if (t == 0) {
      float inv = g1[c] / sqrtf(v1[c] + EPSF);
      float bb = be1[c] - m1[c] * inv;
      float lo = fmaxf(fmaf(mn, inv, bb), 0.0f);
      float hi = fmaxf(fmaf(mx, inv, bb), 0.0f);
      p1[bid] = make_float2(lo, hi);
    }
  } else if (bid == SCAN_BLOCKS) {
    // whole w1 (128x512 f32) in one block: minmax, then quantize
    const f32x4* w4 = (const f32x4*)w1;
    float mn = 3.4e38f, mx = -3.4e38f;
#pragma unroll 8
    for (int k = t; k < 16384; k += 256) {
      f32x4 v = w4[k];
#pragma unroll
      for (int j = 0; j < 4; j++) {
        float f = finz(v[j]); mn = fminf(mn, f); mx = fmaxf(mx, f);
      }
    }
    block_minmax(mn, mx);
    if (t == 0) { bc[0] = mn; bc[1] = mx; }
    __syncthreads();
    const float mnv = bc[0];
    const float s = fmaxf((bc[1] - mnv) / 255.0f, 1e-8f);
    const float rs = 1.0f / s;
#pragma unroll 4
    for (int k = t; k < 16384; k += 256) {
      f32x4 v = w4[k];
      u16x4 o;
#pragma unroll
      for (int j = 0; j < 4; j++)
        o[j] = f2bf(fmaf(rintf((finz(v[j]) - mnv) * rs), s, mnv));
      *(u16x4*)(wq1 + k * 4) = o;
    }
  } else if (bid == SCAN_BLOCKS + 1) {
    // whole w2 (32x128x3x3 f32) in one block: minmax, quant+pack
    const f32x4* w4 = (const f32x4*)w2;
    float mn = 3.4e38f, mx = -3.4e38f;
#pragma unroll 4
    for (int k = t; k < 9216; k += 256) {
      f32x4 v = w4[k];
#pragma unroll
      for (int j = 0; j < 4; j++) {
        float f = finz(v[j]); mn = fminf(mn, f); mx = fmaxf(mx, f);
      }
    }
    block_minmax(mn, mx);
    if (t == 0) { bc[0] = mn; bc[1] = mx; }
    __syncthreads();
    const float mnv = bc[0];
    const float s = fmaxf((bc[1] - mnv) / 255.0f, 1e-8f);
    const float rs = 1.0f / s;
    // wq2 layout: tap*4096 + co*128 + ci  <- w2[(co*128+ci)*9 + tap]
    for (int jj = t; jj < 36864; jj += 256) {
      int tap = jj >> 12;
      int rem = jj & 4095;
      float f = finz(w2[rem * 9 + tap]);
      wq2[jj] = f2bf(fmaf(rintf((f - mnv) * rs), s, mnv));
    }
  } else {
    // bn1/bn2 tables for conv1/conv2 (baseline kwA role)
    float* bn1i = (float*)(ws + WS_BN1I);
    float* bn1b = (float*)(ws + WS_BN1B);
    float* bn2i = (float*)(ws + WS_BN2I);
    float* bn2b = (float*)(ws + WS_BN2B);
    for (int c = t; c < C1; c += 256) {
      float inv = g1[c] / sqrtf(v1[c] + EPSF);
      bn1i[c] = inv;
      bn1b[c] = be1[c] - m1[c] * inv;
    }
    if (t < C2) {
      float inv = g2[t] / sqrtf(v2[t] + EPSF);
      bn2i[t] = inv;
      bn2b[t] = be2[t] - m2[t] * inv;
    }
  }
}

// ---------------------------------------------------------------------------
// conv1: 1x1 conv MFMA GEMM, tile 128co x 128sp, double-buffered LDS,
// one barrier per K-iter (verified baseline form; BN tables from ws).
// ---------------------------------------------------------------------------
__global__ __launch_bounds__(256) void conv1_kernel(const float* __restrict__ x,
                                                    unsigned char* ws) {
  const float* bn1i = (const float*)(ws + WS_BN1I);
  const float* bn1b = (const float*)(ws + WS_BN1B);
  const float* bn2i = (const float*)(ws + WS_BN2I);
  const float* bn2b = (const float*)(ws + WS_BN2B);
  const u16* wq1 = (const u16*)(ws + WS_WQ1);
  const float2* p1 = (const float2*)(ws + WS_P1);
  float2* p2 = (float2*)(ws + WS_P2);
  u16* h2 = (u16*)(ws + WS_H2);

  __shared__ __align__(16) u16 Alds[2][128 * 40];
  __shared__ __align__(16) u16 Blds[2][128 * 40];
  __shared__ float bc[2];
  __shared__ float wred[8];

  const int t = threadIdx.x;
  const int sp0 = blockIdx.x * 128;

  // preamble: reduce 1024 transformed channel partials
  {
    float mn = 3.4e38f, mx = 0.0f;
    for (int i = t; i < SCAN_BLOCKS; i += 256) {
      float2 p = p1[i];
      mn = fminf(mn, p.x); mx = fmaxf(mx, p.y);
    }
    block_minmax(mn, mx);
    if (t == 0) { bc[0] = mn; bc[1] = mx; }
    __syncthreads();
  }
  const float mn1 = bc[0];
  const float s1 = fmaxf((bc[1] - mn1) / 255.0f, 1e-8f);
  const float r1 = 1.0f / s1;

  // x staging: thread -> k-row kk (0..31), sp groups of 8 in both halves
  const int kk = t >> 3;
  const int spA = (t & 7) * 8;
  const int spB = 64 + spA;
  const int ga = sp0 + spA, gb = sp0 + spB;
  const int na = ga / HW, hwa = ga % HW;
  const int nb = gb / HW, hwb = gb % HW;
  const float* xA = x + na * (C1 * HW) + hwa;
  const float* xB = x + nb * (C1 * HW) + hwb;
  const int colg = (kk & 7) + 8 * ((((kk >> 3) + (spA >> 3))) & 3);

  // wq1 staging: thread -> co = t>>1, k offset (t&1)*16
  const int wco = t >> 1;
  const int wko = (t & 1) * 16;
  const int ab0 = wko >> 3;
  const int aswz = (wco >> 3) & 3;

  const int lane = t & 63;
  const int l15 = lane & 15;
  const int q = lane >> 4;
  const int wv = t >> 6;
  const int wy = wv >> 1;
  const int wx = wv & 1;

  f32x4 acc[4][4] = {};

  // prologue: load k=0 slice into registers
  u16x8 a0 = *(const u16x8*)(wq1 + wco * C1 + wko);
  u16x8 a1 = *(const u16x8*)(wq1 + wco * C1 + wko + 8);
  f32x4 va0 = *(const f32x4*)(xA + kk * HW);
  f32x4 va1 = *(const f32x4*)(xA + kk * HW + 4);
  f32x4 vb0 = *(const f32x4*)(xB + kk * HW);
  f32x4 vb1 = *(const f32x4*)(xB + kk * HW + 4);
  float inv = bn1i[kk], bb = bn1b[kk];

#pragma unroll 1
  for (int i = 0; i < 16; i++) {
    const int cur = i & 1;
    *(u16x8*)&Alds[cur][wco * 40 + (((ab0 + 0 + aswz) & 3) << 3)] = a0;
    *(u16x8*)&Alds[cur][wco * 40 + (((ab0 + 1 + aswz) & 3) << 3)] = a1;
#pragma unroll
    for (int j = 0; j < 4; j++) {
      float f0 = fmaxf(fmaf(va0[j], inv, bb), 0.0f);
      Blds[cur][(spA + j) * 40 + colg] = f2bf(fmaf(rintf((f0 - mn1) * r1), s1, mn1));
      float f1 = fmaxf(fmaf(va1[j], inv, bb), 0.0f);
      Blds[cur][(spA + 4 + j) * 40 + colg] = f2bf(fmaf(rintf((f1 - mn1) * r1), s1, mn1));
      float g0 = fmaxf(fmaf(vb0[j], inv, bb), 0.0f);
      Blds[cur][(spB + j) * 40 + colg] = f2bf(fmaf(rintf((g0 - mn1) * r1), s1, mn1));
      float g1v = fmaxf(fmaf(vb1[j], inv, bb), 0.0f);
      Blds[cur][(spB + 4 + j) * 40 + colg] = f2bf(fmaf(rintf((g1v - mn1) * r1), s1, mn1));
    }
    if (i < 15) {
      const int kn = (i + 1) * 32;
      a0 = *(const u16x8*)(wq1 + wco * C1 + kn + wko);
      a1 = *(const u16x8*)(wq1 + wco * C1 + kn + wko + 8);
      const int c = kn + kk;
      va0 = *(const f32x4*)(xA + c * HW);
      va1 = *(const f32x4*)(xA + c * HW + 4);
      vb0 = *(const f32x4*)(xB + c * HW);
      vb1 = *(const f32x4*)(xB + c * HW + 4);
      inv = bn1i[c]; bb = bn1b[c];
    }
    __syncthreads();
    bf16x8 af[4], bfr[4];
#pragma unroll
    for (int ii = 0; ii < 4; ii++) {
      int R = wy * 64 + ii * 16 + l15;
      af[ii] = *(const bf16x8*)&Alds[cur][R * 40 + (((q + (R >> 3)) & 3) << 3)];
    }
#pragma unroll
    for (int j = 0; j < 4; j++) {
      int R = wx * 64 + j * 16 + l15;
      bfr[j] = *(const bf16x8*)&Blds[cur][R * 40 + (((q + (R >> 3)) & 3) << 3)];
    }
#pragma unroll
    for (int ii = 0; ii < 4; ii++)
#pragma unroll
      for (int j = 0; j < 4; j++)
        acc[ii][j] = __builtin_amdgcn_mfma_f32_16x16x32_bf16(af[ii], bfr[j], acc[ii][j], 0, 0, 0);
  }

  // epilogue: bn2 + relu, store raw h2 NHWC bf16, per-block min/max partial
  float lmn = 3.4e38f, lmx = 0.0f;
#pragma unroll
  for (int i = 0; i < 4; i++) {
    int cob = wy * 64 + i * 16 + q * 4;
    f32x4 i2 = *(const f32x4*)&bn2i[cob];
    f32x4 b2 = *(const f32x4*)&bn2b[cob];
#pragma unroll
    for (int j = 0; j < 4; j++) {
      int sp = sp0 + wx * 64 + j * 16 + l15;
      u16x4 v;
#pragma unroll
      for (int r = 0; r < 4; r++) {
        float h = fmaxf(fmaf(acc[i][j][r], i2[r], b2[r]), 0.0f);
        v[r] = f2bf(h);
        lmn = fminf(lmn, h); lmx = fmaxf(lmx, h);
      }
      *(u16x4*)&h2[sp * C2 + cob] = v;
    }
  }
  for (int m = 32; m; m >>= 1) {
    lmn = fminf(lmn, __shfl_xor(lmn, m));
    lmx = fmaxf(lmx, __shfl_xor(lmx, m));
  }
  if (lane == 0) { wred[wv] = lmn; wred[4 + wv] = lmx; }
  __syncthreads();
  if (t == 0) {
    float2 pr;
    pr.x = fminf(fminf(wred[0], wred[1]), fminf(wred[2], wred[3]));
    pr.y = fmaxf(fmaxf(wred[4], wred[5]), fmaxf(wred[6], wred[7]));
    p2[blockIdx.x] = pr;
  }
}

// ---------------------------------------------------------------------------
// conv2: 3x3 conv (pad 1) direct MFMA, inline h2 quant, XCD-aware swizzle.
// ---------------------------------------------------------------------------
__global__ __launch_bounds__(256) void conv2_kernel(const unsigned char* ws,
                                                    float* __restrict__ out) {
  const u16* wq2 = (const u16*)(ws + WS_WQ2);
  const u16* h2 = (const u16*)(ws + WS_H2);
  const float2* p2 = (const float2*)(ws + WS_P2);
  __shared__ float bc2[2];

  const int t = threadIdx.x;
  {  // preamble: reduce 392 conv1-partials
    float mn = 3.4e38f, mx = 0.0f;
    for (int i = t; i < CONV1_BLOCKS; i += 256) {
      float2 p = p2[i];
      mn = fminf(mn, p.x); mx = fmaxf(mx, p.y);
    }
    block_minmax(mn, mx);
    if (t == 0) { bc2[0] = mn; bc2[1] = mx; }
    __syncthreads();
  }
  const float mn2 = bc2[0];
  const float s2 = fmaxf((bc2[1] - mn2) / 255.0f, 1e-8f);
  const float r2 = 1.0f / s2;

  const int lane = t & 63;
  const int l15 = lane & 15;
  const int q = lane >> 4;
  const int wv = t >> 6;

  const int B = blockIdx.x;
  const int sblk = (B & 7) * 98 + (B >> 3);    // XCD-contiguous sp mapping
  const int spf = sblk * 64 + wv * 16 + l15;
  const int nn = spf / HW;
  const int hwf = spf % HW;
  const int hf = hwf / WW;
  const int wf = hwf % WW;

  f32x4 acc[2] = {};
  bf16x8 bz;
#pragma unroll
  for (int j = 0; j < 8; j++) bz[j] = 0;

  for (int tap = 0; tap < 9; tap++) {
    const int dh = tap / 3 - 1, dw = tap % 3 - 1;
    const u16* wA = wq2 + tap * (C3 * C2);
    unsigned h2i = (unsigned)(hf + dh);
    unsigned w2i = (unsigned)(wf + dw);
    const bool val = (h2i < 28u) && (w2i < 28u);
    const u16* bptr = h2 + ((size_t)(nn * HW + (int)h2i * WW + (int)w2i)) * C2;
#pragma unroll
    for (int ks = 0; ks < C2; ks += 32) {
      bf16x8 a[2], b;
#pragma unroll
      for (int f = 0; f < 2; f++)
        a[f] = *(const bf16x8*)(wA + (f * 16 + l15) * C2 + ks + q * 8);
      if (val) {
        u16x8 hv = *(const u16x8*)(bptr + ks + q * 8);
#pragma unroll
        for (int j = 0; j < 8; j++) {
          float h = bf2f(hv[j]);
          b[j] = (short)f2bf(fmaf(rintf((h - mn2) * r2), s2, mn2));
        }
      } else {
        b = bz;
      }
#pragma unroll
      for (int i = 0; i < 2; i++)
        acc[i] = __builtin_amdgcn_mfma_f32_16x16x32_bf16(a[i], b, acc[i], 0, 0, 0);
    }
  }

#pragma unroll
  for (int i = 0; i < 2; i++) {
    int co = i * 16 + q * 4;
#pragma unroll
    for (int r = 0; r < 4; r++)
      out[(nn * C3 + co + r) * HW + hwf] = acc[i][r];
  }
}

// ---------------------------------------------------------------------------
extern "C" void kernel_launch(void* const* d_in, const int* in_sizes, int n_in,
                              void* d_out, int out_size, void* d_ws, size_t ws_size,
                              hipStream_t stream) {
  const float* x  = (const float*)d_in[0];
  const float* g1 = (const float*)d_in[1];
  const float* b1 = (const float*)d_in[2];
  const float* m1 = (const float*)d_in[3];
  const float* v1 = (const float*)d_in[4];
  const float* w1 = (const float*)d_in[5];
  const float* g2 = (const float*)d_in[6];
  const float* b2 = (const float*)d_in[7];
  const float* m2 = (const float*)d_in[8];
  const float* v2 = (const float*)d_in[9];
  const float* w2 = (const float*)d_in[10];
  unsigned char* ws = (unsigned char*)d_ws;
  float* out = (float*)d_out;

  kA_kernel<<<KA_GRID, 256, 0, stream>>>(x, g1, b1, m1, v1, w1, g2, b2, m2, v2, w2, ws);
  conv1_kernel<<<CONV1_BLOCKS, 256, 0, stream>>>(x, ws);
  conv2_kernel<<<CONV2_BLOCKS, 256, 0, stream>>>(ws, out);
}

// Round 10
// 246.455 us; speedup vs baseline: 2.3979x; 1.0647x over previous
//
#include <hip/hip_runtime.h>

typedef unsigned short u16;
typedef unsigned short u16x4 __attribute__((ext_vector_type(4)));
typedef unsigned short u16x8 __attribute__((ext_vector_type(8)));
typedef short bf16x8 __attribute__((ext_vector_type(8)));
typedef float f32x4 __attribute__((ext_vector_type(4)));

#define EPSF 1e-5f

// Geometry
#define C1   512
#define C2   128
#define C3   32
#define HH   28
#define WW   28
#define HW   784            // 28*28
#define NHW  50176          // 64*784

#define SCAN_BLOCKS 1024    // (channel, batch-half) pairs: 512 x 2
#define W1P_BLOCKS  64      // w1 minmax partial blocks
#define W2P_BLOCKS  16      // w2 minmax partial blocks
#define KA_GRID     1105    // 1024 scan + 64 w1 + 16 w2 + 1 bn-table
#define KWB_BLOCKS  80      // 64 w1-quant + 16 w2-quant blocks
#define CONV1_BLOCKS 392    // NHW/128
#define CONV2_BLOCKS 784    // NHW/64

// ws layout (bytes)
#define WS_BN1I   64        // 512 f32
#define WS_BN1B   2112      // 512 f32
#define WS_BN2I   4160      // 128 f32
#define WS_BN2B   4672      // 128 f32 -> ends 5184
#define WS_WQ1    5376      // 128*512 bf16   -> ends 136448
#define WS_WQ2    136448    // 9*32*128 bf16  -> ends 210176
#define WS_P1     210176    // 1024 float2 transformed channel partials -> ends 218368
#define WS_P2     226560    // 392 float2 partials (conv1) -> ends 229696
#define WS_PW1    232832    // 64 float2 partials (w1)
#define WS_PW2    233344    // 16 float2 partials (w2) -> ends 233472
#define WS_H2     233472    // 50176*128 bf16 (NHWC)

__device__ __forceinline__ float bf2f(u16 u) { return __uint_as_float(((unsigned)u) << 16); }
__device__ __forceinline__ u16 f2bf(float f) {
  unsigned x = __float_as_uint(f);
  return (u16)((x + 0x7fffu + ((x >> 16) & 1u)) >> 16);
}
__device__ __forceinline__ float finz(float f) {
  unsigned u = __float_as_uint(f);
  return ((u & 0x7f800000u) == 0x7f800000u) ? 0.0f : f;
}

// block-level min/max reduce; result valid on threadIdx.x==0
__device__ __forceinline__ void block_minmax(float& mn, float& mx) {
  for (int m = 32; m; m >>= 1) {
    mn = fminf(mn, __shfl_xor(mn, m));
    mx = fmaxf(mx, __shfl_xor(mx, m));
  }
  __shared__ float wmn[4], wmx[4];
  const int wv = threadIdx.x >> 6;
  if ((threadIdx.x & 63) == 0) { wmn[wv] = mn; wmx[wv] = mx; }
  __syncthreads();
  if (threadIdx.x == 0) {
    mn = fminf(fminf(wmn[0], wmn[1]), fminf(wmn[2], wmn[3]));
    mx = fmaxf(fmaxf(wmx[0], wmx[1]), fmaxf(wmx[2], wmx[3]));
  }
}

// ---------------------------------------------------------------------------
// kA: blocks 0..1023   -> per-(channel, batch-half) RAW x min/max, one
//                         monotone bn+relu transform at block end (exact).
//     blocks 1024..1087 -> w1 minmax partials (1 f32x4/thread, baseline kwA)
//     blocks 1088..1103 -> w2 minmax partials (9 loads/thread, baseline kwA)
//     block  1104       -> bn1/bn2 tables
// R9 post-mortem: the single-block whole-w2 quantize (144 scattered scalar
// loads/thread on ONE CU) was a ~30us straggler that defined kA's 60us
// duration across two scan rewrites. Weight work now spread over 80 blocks
// (partials here, quantize in kwB) exactly like the verified baseline.
// ---------------------------------------------------------------------------
__global__ __launch_bounds__(256) void kA_kernel(
    const float* __restrict__ x, const float* g1, const float* be1,
    const float* m1, const float* v1, const float* w1,
    const float* g2, const float* be2, const float* m2, const float* v2,
    const float* w2, unsigned char* ws) {
  const int t = threadIdx.x;
  const int bid = blockIdx.x;
  float2* p1 = (float2*)(ws + WS_P1);
  float2* pw1 = (float2*)(ws + WS_PW1);
  float2* pw2 = (float2*)(ws + WS_PW2);

  if (bid < SCAN_BLOCKS) {
    const int c = bid >> 1;
    const int n0 = (bid & 1) << 5;   // batch half: n in [n0, n0+32)
    const f32x4* xb = (const f32x4*)x + ((size_t)n0 * C1 + c) * 196;
    float mn0 = 3.4e38f, mx0 = -3.4e38f, mn1 = 3.4e38f, mx1 = -3.4e38f;
    float mn2 = 3.4e38f, mx2 = -3.4e38f, mn3 = 3.4e38f, mx3 = -3.4e38f;
    auto P = [&](int j, float& mn, float& mx) {
      int s = j / 196;               // segment (batch index offset)
      int g = j - s * 196;           // f32x4 column within row
      f32x4 v = xb[(size_t)s * (C1 * 196) + g];
      mn = fminf(mn, fminf(fminf(v[0], v[1]), fminf(v[2], v[3])));
      mx = fmaxf(mx, fmaxf(fmaxf(v[0], v[1]), fmaxf(v[2], v[3])));
    };
    int j = t;
    for (; j + 768 < 6272; j += 1024) {
      P(j, mn0, mx0); P(j + 256, mn1, mx1);
      P(j + 512, mn2, mx2); P(j + 768, mn3, mx3);
    }
    for (; j < 6272; j += 256) P(j, mn0, mx0);
    float mn = fminf(fminf(mn0, mn1), fminf(mn2, mn3));
    float mx = fmaxf(fmaxf(mx0, mx1), fmaxf(mx2, mx3));
    block_minmax(mn, mx);
    if (t == 0) {
      float inv = g1[c] / sqrtf(v1[c] + EPSF);
      float bb = be1[c] - m1[c] * inv;
      float lo = fmaxf(fmaf(mn, inv, bb), 0.0f);
      float hi = fmaxf(fmaf(mx, inv, bb), 0.0f);
      p1[bid] = make_float2(lo, hi);
    }
  } else if (bid < SCAN_BLOCKS + W1P_BLOCKS) {
    const int b = bid - SCAN_BLOCKS;
    float mn = 3.4e38f, mx = -3.4e38f;
    f32x4 v = *(const f32x4*)(w1 + b * 1024 + t * 4);
#pragma unroll
    for (int j = 0; j < 4; j++) {
      float f = finz(v[j]); mn = fminf(mn, f); mx = fmaxf(mx, f);
    }
    block_minmax(mn, mx);
    if (t == 0) pw1[b] = make_float2(mn, mx);
  } else if (bid < SCAN_BLOCKS + W1P_BLOCKS + W2P_BLOCKS) {
    const int b = bid - SCAN_BLOCKS - W1P_BLOCKS;
    const int base = b * 2304;
    float mn = 3.4e38f, mx = -3.4e38f;
#pragma unroll
    for (int j = 0; j < 9; j++) {
      float f = finz(w2[base + t + j * 256]);
      mn = fminf(mn, f); mx = fmaxf(mx, f);
    }
    block_minmax(mn, mx);
    if (t == 0) pw2[b] = make_float2(mn, mx);
  } else {
    // bn1/bn2 tables for conv1/conv2
    float* bn1i = (float*)(ws + WS_BN1I);
    float* bn1b = (float*)(ws + WS_BN1B);
    float* bn2i = (float*)(ws + WS_BN2I);
    float* bn2b = (float*)(ws + WS_BN2B);
    for (int c = t; c < C1; c += 256) {
      float inv = g1[c] / sqrtf(v1[c] + EPSF);
      bn1i[c] = inv;
      bn1b[c] = be1[c] - m1[c] * inv;
    }
    if (t < C2) {
      float inv = g2[t] / sqrtf(v2[t] + EPSF);
      bn2i[t] = inv;
      bn2b[t] = be2[t] - m2[t] * inv;
    }
  }
}

// ---------------------------------------------------------------------------
// kwB: reduce weight partials, quantize w1 -> wq1, quantize+pack w2 -> wq2.
// (baseline-verified form, 80 blocks)
// ---------------------------------------------------------------------------
__global__ __launch_bounds__(256) void kwB_kernel(const float* w1, const float* w2,
                                                  unsigned char* ws) {
  const float2* pw1 = (const float2*)(ws + WS_PW1);
  const float2* pw2 = (const float2*)(ws + WS_PW2);
  u16* wq1 = (u16*)(ws + WS_WQ1);
  u16* wq2 = (u16*)(ws + WS_WQ2);
  const int t = threadIdx.x;
  const int b = blockIdx.x;
  __shared__ float bc[2];

  if (b < 64) {
    if (t < 64) {
      float2 p = pw1[t];
      float mn = p.x, mx = p.y;
      for (int m = 32; m; m >>= 1) {
        mn = fminf(mn, __shfl_xor(mn, m));
        mx = fmaxf(mx, __shfl_xor(mx, m));
      }
      if (t == 0) { bc[0] = mn; bc[1] = mx; }
    }
    __syncthreads();
    const float mn = bc[0];
    const float s = fmaxf((bc[1] - mn) / 255.0f, 1e-8f);
    const float rs = 1.0f / s;
    f32x4 v = *(const f32x4*)(w1 + b * 1024 + t * 4);
    u16x4 o;
#pragma unroll
    for (int j = 0; j < 4; j++)
      o[j] = f2bf(fmaf(rintf((finz(v[j]) - mn) * rs), s, mn));
    *(u16x4*)(wq1 + b * 1024 + t * 4) = o;
  } else {
    if (t < 64) {
      float2 p = (t < 16) ? pw2[t] : make_float2(3.4e38f, -3.4e38f);
      float mn = p.x, mx = p.y;
      for (int m = 32; m; m >>= 1) {
        mn = fminf(mn, __shfl_xor(mn, m));
        mx = fmaxf(mx, __shfl_xor(mx, m));
      }
      if (t == 0) { bc[0] = mn; bc[1] = mx; }
    }
    __syncthreads();
    const float mn = bc[0];
    const float s = fmaxf((bc[1] - mn) / 255.0f, 1e-8f);
    const float rs = 1.0f / s;
    const int base = (b - 64) * 2304;
#pragma unroll
    for (int j = 0; j < 9; j++) {
      int o = base + t + j * 256;       // o = tap*4096 + co*128 + ci
      int tap = o >> 12;
      int rem = o & 4095;
      float f = finz(w2[rem * 9 + tap]);
      wq2[o] = f2bf(fmaf(rintf((f - mn) * rs), s, mn));
    }
  }
}

// ---------------------------------------------------------------------------
// conv1: 1x1 conv MFMA GEMM, tile 128co x 128sp, double-buffered LDS,
// one barrier per K-iter (verified baseline form; BN tables from ws).
// ---------------------------------------------------------------------------
__global__ __launch_bounds__(256) void conv1_kernel(const float* __restrict__ x,
                                                    unsigned char* ws) {
  const float* bn1i = (const float*)(ws + WS_BN1I);
  const float* bn1b = (const float*)(ws + WS_BN1B);
  const float* bn2i = (const float*)(ws + WS_BN2I);
  const float* bn2b = (const float*)(ws + WS_BN2B);
  const u16* wq1 = (const u16*)(ws + WS_WQ1);
  const float2* p1 = (const float2*)(ws + WS_P1);
  float2* p2 = (float2*)(ws + WS_P2);
  u16* h2 = (u16*)(ws + WS_H2);

  __shared__ __align__(16) u16 Alds[2][128 * 40];
  __shared__ __align__(16) u16 Blds[2][128 * 40];
  __shared__ float bc[2];
  __shared__ float wred[8];

  const int t = threadIdx.x;
  const int sp0 = blockIdx.x * 128;

  // preamble: reduce 1024 transformed channel partials
  {
    float mn = 3.4e38f, mx = 0.0f;
    for (int i = t; i < SCAN_BLOCKS; i += 256) {
      float2 p = p1[i];
      mn = fminf(mn, p.x); mx = fmaxf(mx, p.y);
    }
    block_minmax(mn, mx);
    if (t == 0) { bc[0] = mn; bc[1] = mx; }
    __syncthreads();
  }
  const float mn1 = bc[0];
  const float s1 = fmaxf((bc[1] - mn1) / 255.0f, 1e-8f);
  const float r1 = 1.0f / s1;

  // x staging: thread -> k-row kk (0..31), sp groups of 8 in both halves
  const int kk = t >> 3;
  const int spA = (t & 7) * 8;
  const int spB = 64 + spA;
  const int ga = sp0 + spA, gb = sp0 + spB;
  const int na = ga / HW, hwa = ga % HW;
  const int nb = gb / HW, hwb = gb % HW;
  const float* xA = x + na * (C1 * HW) + hwa;
  const float* xB = x + nb * (C1 * HW) + hwb;
  const int colg = (kk & 7) + 8 * ((((kk >> 3) + (spA >> 3))) & 3);

  // wq1 staging: thread -> co = t>>1, k offset (t&1)*16
  const int wco = t >> 1;
  const int wko = (t & 1) * 16;
  const int ab0 = wko >> 3;
  const int aswz = (wco >> 3) & 3;

  const int lane = t & 63;
  const int l15 = lane & 15;
  const int q = lane >> 4;
  const int wv = t >> 6;
  const int wy = wv >> 1;
  const int wx = wv & 1;

  f32x4 acc[4][4] = {};

  // prologue: load k=0 slice into registers
  u16x8 a0 = *(const u16x8*)(wq1 + wco * C1 + wko);
  u16x8 a1 = *(const u16x8*)(wq1 + wco * C1 + wko + 8);
  f32x4 va0 = *(const f32x4*)(xA + kk * HW);
  f32x4 va1 = *(const f32x4*)(xA + kk * HW + 4);
  f32x4 vb0 = *(const f32x4*)(xB + kk * HW);
  f32x4 vb1 = *(const f32x4*)(xB + kk * HW + 4);
  float inv = bn1i[kk], bb = bn1b[kk];

#pragma unroll 1
  for (int i = 0; i < 16; i++) {
    const int cur = i & 1;
    *(u16x8*)&Alds[cur][wco * 40 + (((ab0 + 0 + aswz) & 3) << 3)] = a0;
    *(u16x8*)&Alds[cur][wco * 40 + (((ab0 + 1 + aswz) & 3) << 3)] = a1;
#pragma unroll
    for (int j = 0; j < 4; j++) {
      float f0 = fmaxf(fmaf(va0[j], inv, bb), 0.0f);
      Blds[cur][(spA + j) * 40 + colg] = f2bf(fmaf(rintf((f0 - mn1) * r1), s1, mn1));
      float f1 = fmaxf(fmaf(va1[j], inv, bb), 0.0f);
      Blds[cur][(spA + 4 + j) * 40 + colg] = f2bf(fmaf(rintf((f1 - mn1) * r1), s1, mn1));
      float g0 = fmaxf(fmaf(vb0[j], inv, bb), 0.0f);
      Blds[cur][(spB + j) * 40 + colg] = f2bf(fmaf(rintf((g0 - mn1) * r1), s1, mn1));
      float g1v = fmaxf(fmaf(vb1[j], inv, bb), 0.0f);
      Blds[cur][(spB + 4 + j) * 40 + colg] = f2bf(fmaf(rintf((g1v - mn1) * r1), s1, mn1));
    }
    if (i < 15) {
      const int kn = (i + 1) * 32;
      a0 = *(const u16x8*)(wq1 + wco * C1 + kn + wko);
      a1 = *(const u16x8*)(wq1 + wco * C1 + kn + wko + 8);
      const int c = kn + kk;
      va0 = *(const f32x4*)(xA + c * HW);
      va1 = *(const f32x4*)(xA + c * HW + 4);
      vb0 = *(const f32x4*)(xB + c * HW);
      vb1 = *(const f32x4*)(xB + c * HW + 4);
      inv = bn1i[c]; bb = bn1b[c];
    }
    __syncthreads();
    bf16x8 af[4], bfr[4];
#pragma unroll
    for (int ii = 0; ii < 4; ii++) {
      int R = wy * 64 + ii * 16 + l15;
      af[ii] = *(const bf16x8*)&Alds[cur][R * 40 + (((q + (R >> 3)) & 3) << 3)];
    }
#pragma unroll
    for (int j = 0; j < 4; j++) {
      int R = wx * 64 + j * 16 + l15;
      bfr[j] = *(const bf16x8*)&Blds[cur][R * 40 + (((q + (R >> 3)) & 3) << 3)];
    }
#pragma unroll
    for (int ii = 0; ii < 4; ii++)
#pragma unroll
      for (int j = 0; j < 4; j++)
        acc[ii][j] = __builtin_amdgcn_mfma_f32_16x16x32_bf16(af[ii], bfr[j], acc[ii][j], 0, 0, 0);
  }

  // epilogue: bn2 + relu, store raw h2 NHWC bf16, per-block min/max partial
  float lmn = 3.4e38f, lmx = 0.0f;
#pragma unroll
  for (int i = 0; i < 4; i++) {
    int cob = wy * 64 + i * 16 + q * 4;
    f32x4 i2 = *(const f32x4*)&bn2i[cob];
    f32x4 b2 = *(const f32x4*)&bn2b[cob];
#pragma unroll
    for (int j = 0; j < 4; j++) {
      int sp = sp0 + wx * 64 + j * 16 + l15;
      u16x4 v;
#pragma unroll
      for (int r = 0; r < 4; r++) {
        float h = fmaxf(fmaf(acc[i][j][r], i2[r], b2[r]), 0.0f);
        v[r] = f2bf(h);
        lmn = fminf(lmn, h); lmx = fmaxf(lmx, h);
      }
      *(u16x4*)&h2[sp * C2 + cob] = v;
    }
  }
  for (int m = 32; m; m >>= 1) {
    lmn = fminf(lmn, __shfl_xor(lmn, m));
    lmx = fmaxf(lmx, __shfl_xor(lmx, m));
  }
  if (lane == 0) { wred[wv] = lmn; wred[4 + wv] = lmx; }
  __syncthreads();
  if (t == 0) {
    float2 pr;
    pr.x = fminf(fminf(wred[0], wred[1]), fminf(wred[2], wred[3]));
    pr.y = fmaxf(fmaxf(wred[4], wred[5]), fmaxf(wred[6], wred[7]));
    p2[blockIdx.x] = pr;
  }
}

// ---------------------------------------------------------------------------
// conv2: 3x3 conv (pad 1) direct MFMA, inline h2 quant, XCD-aware swizzle.
// ---------------------------------------------------------------------------
__global__ __launch_bounds__(256) void conv2_kernel(const unsigned char* ws,
                                                    float* __restrict__ out) {
  const u16* wq2 = (const u16*)(ws + WS_WQ2);
  const u16* h2 = (const u16*)(ws + WS_H2);
  const float2* p2 = (const float2*)(ws + WS_P2);
  __shared__ float bc2[2];

  const int t = threadIdx.x;
  {  // preamble: reduce 392 conv1-partials
    float mn = 3.4e38f, mx = 0.0f;
    for (int i = t; i < CONV1_BLOCKS; i += 256) {
      float2 p = p2[i];
      mn = fminf(mn, p.x); mx = fmaxf(mx, p.y);
    }
    block_minmax(mn, mx);
    if (t == 0) { bc2[0] = mn; bc2[1] = mx; }
    __syncthreads();
  }
  const float mn2 = bc2[0];
  const float s2 = fmaxf((bc2[1] - mn2) / 255.0f, 1e-8f);
  const float r2 = 1.0f / s2;

  const int lane = t & 63;
  const int l15 = lane & 15;
  const int q = lane >> 4;
  const int wv = t >> 6;

  const int B = blockIdx.x;
  const int sblk = (B & 7) * 98 + (B >> 3);    // XCD-contiguous sp mapping
  const int spf = sblk * 64 + wv * 16 + l15;
  const int nn = spf / HW;
  const int hwf = spf % HW;
  const int hf = hwf / WW;
  const int wf = hwf % WW;

  f32x4 acc[2] = {};
  bf16x8 bz;
#pragma unroll
  for (int j = 0; j < 8; j++) bz[j] = 0;

  for (int tap = 0; tap < 9; tap++) {
    const int dh = tap / 3 - 1, dw = tap % 3 - 1;
    const u16* wA = wq2 + tap * (C3 * C2);
    unsigned h2i = (unsigned)(hf + dh);
    unsigned w2i = (unsigned)(wf + dw);
    const bool val = (h2i < 28u) && (w2i < 28u);
    const u16* bptr = h2 + ((size_t)(nn * HW + (int)h2i * WW + (int)w2i)) * C2;
#pragma unroll
    for (int ks = 0; ks < C2; ks += 32) {
      bf16x8 a[2], b;
#pragma unroll
      for (int f = 0; f < 2; f++)
        a[f] = *(const bf16x8*)(wA + (f * 16 + l15) * C2 + ks + q * 8);
      if (val) {
        u16x8 hv = *(const u16x8*)(bptr + ks + q * 8);
#pragma unroll
        for (int j = 0; j < 8; j++) {
          float h = bf2f(hv[j]);
          b[j] = (short)f2bf(fmaf(rintf((h - mn2) * r2), s2, mn2));
        }
      } else {
        b = bz;
      }
#pragma unroll
      for (int i = 0; i < 2; i++)
        acc[i] = __builtin_amdgcn_mfma_f32_16x16x32_bf16(a[i], b, acc[i], 0, 0, 0);
    }
  }

#pragma unroll
  for (int i = 0; i < 2; i++) {
    int co = i * 16 + q * 4;
#pragma unroll
    for (int r = 0; r < 4; r++)
      out[(nn * C3 + co + r) * HW + hwf] = acc[i][r];
  }
}

// ---------------------------------------------------------------------------
extern "C" void kernel_launch(void* const* d_in, const int* in_sizes, int n_in,
                              void* d_out, int out_size, void* d_ws, size_t ws_size,
                              hipStream_t stream) {
  const float* x  = (const float*)d_in[0];
  const float* g1 = (const float*)d_in[1];
  const float* b1 = (const float*)d_in[2];
  const float* m1 = (const float*)d_in[3];
  const float* v1 = (const float*)d_in[4];
  const float* w1 = (const float*)d_in[5];
  const float* g2 = (const float*)d_in[6];
  const float* b2 = (const float*)d_in[7];
  const float* m2 = (const float*)d_in[8];
  const float* v2 = (const float*)d_in[9];
  const float* w2 = (const float*)d_in[10];
  unsigned char* ws = (unsigned char*)d_ws;
  float* out = (float*)d_out;

  kA_kernel<<<KA_GRID, 256, 0, stream>>>(x, g1, b1, m1, v1, w1, g2, b2, m2, v2, w2, ws);
  kwB_kernel<<<KWB_BLOCKS, 256, 0, stream>>>(w1, w2, ws);
  conv1_kernel<<<CONV1_BLOCKS, 256, 0, stream>>>(x, ws);
  conv2_kernel<<<CONV2_BLOCKS, 256, 0, stream>>>(ws, out);
}